// Round 4
// baseline (1317.392 us; speedup 1.0000x reference)
//
#include <hip/hip_runtime.h>
#include <math.h>

typedef unsigned short ushort_t;
typedef unsigned int uint_t;

#define D_MODEL 512
#define N_HEADS 8
#define HEAD_D  64
#define D_FFN   2048

__device__ __forceinline__ float bf2f(unsigned short u) {
  union { unsigned int i; float f; } c; c.i = ((unsigned int)u) << 16; return c.f;
}
__device__ __forceinline__ unsigned short f2bf(float f) {
  union { float f; unsigned int i; } c; c.f = f;
  unsigned int x = c.i;
  return (unsigned short)((x + 0x7FFFu + ((x >> 16) & 1u)) >> 16);
}
// flag-switched external load: f==1 -> buffer is f32, else bf16
__device__ __forceinline__ float ldx(const void* p, size_t i, int f) {
  return f ? ((const float*)p)[i] : bf2f(((const ushort_t*)p)[i]);
}

// ------------------------------------------------- dtype detector (1 block)
// Low u16 of each u32 word: bf16 data -> a bf16 code, exp in [0x70,0x83]
// ~always; f32 data -> uniform mantissa bits, in range ~8%. Zeros -> bf16
// (safe: bf16 read is in-bounds for both dtypes and yields correct 0.0).
__global__ __launch_bounds__(256)
void detect_kernel(const void* __restrict__ p, int n_elems, int* __restrict__ flag) {
  __shared__ int cnt[2];
  const int t = threadIdx.x;
  if (t == 0) { cnt[0] = 0; cnt[1] = 0; }
  __syncthreads();
  const int n_u32 = n_elems >> 1;            // bf16-size words: always in-bounds
  const int sample = n_u32 < 256 ? n_u32 : 256;
  if (t < sample) {
    uint_t u = ((const uint_t*)p)[t];
    if (u != 0u) {
      atomicAdd(&cnt[0], 1);
      int e = (u >> 7) & 0xFF;
      if (e >= 0x70 && e <= 0x83) atomicAdd(&cnt[1], 1);
    }
  }
  __syncthreads();
  if (t == 0) *flag = (cnt[0] >= 32 && cnt[1] * 4 <= cnt[0]) ? 1 : 0;
}

// ------------------------------------------------- LN1: x -> bf16 h1
__global__ __launch_bounds__(256)
void ln1_kernel(const void* __restrict__ x, const void* __restrict__ g,
                const void* __restrict__ b, ushort_t* __restrict__ out,
                const int* __restrict__ flags) {
  const int fx = flags[0], fg = flags[2], fb = flags[3];
  const int row = blockIdx.x * 4 + (threadIdx.x >> 6);
  const int lane = threadIdx.x & 63;
  float v[8], sum = 0.f, sq = 0.f;
#pragma unroll
  for (int i = 0; i < 8; ++i) {
    v[i] = ldx(x, (size_t)row * D_MODEL + lane * 8 + i, fx);
    sum += v[i]; sq += v[i] * v[i];
  }
#pragma unroll
  for (int o = 32; o > 0; o >>= 1) { sum += __shfl_xor(sum, o); sq += __shfl_xor(sq, o); }
  const float mu = sum * (1.0f / D_MODEL);
  const float var = sq * (1.0f / D_MODEL) - mu * mu;
  const float rstd = rsqrtf(var + 1e-5f);
#pragma unroll
  for (int i = 0; i < 8; ++i) {
    int c = lane * 8 + i;
    out[(size_t)row * D_MODEL + c] =
        f2bf((v[i] - mu) * rstd * ldx(g, c, fg) + ldx(b, c, fb));
  }
}

// ------------------------------------------------- simple GEMM, K=512 only
// A: M x 512 bf16 (internal). B: 512 x N external (flag). 4 rows/block,
// 256 consecutive cols/thread-block, one col per thread.
// EPI 0: +bias -> bf16.  EPI 2: +bias + res(x, flag) -> f32.
template <int EPI>
__global__ __launch_bounds__(256)
void gemm_simple(const ushort_t* __restrict__ A, const void* __restrict__ B,
                 int N,
                 const void* __restrict__ bias,
                 const void* __restrict__ res,
                 ushort_t* __restrict__ out_bf,
                 float* __restrict__ out_f,
                 const int* __restrict__ flags, int fBi, int fbi, int fri) {
  const int fB = flags[fBi], fb = flags[fbi];
  __shared__ float As[4][512];
  const int t = threadIdx.x;
  const int m0 = blockIdx.y * 4;
  const int col = blockIdx.x * 256 + t;

#pragma unroll
  for (int r = 0; r < 4; ++r)
    for (int k = t; k < 512; k += 256)
      As[r][k] = bf2f(A[(size_t)(m0 + r) * 512 + k]);
  __syncthreads();

  float acc[4] = {0.f, 0.f, 0.f, 0.f};
  for (int k = 0; k < 512; ++k) {
    const float bv = ldx(B, (size_t)k * N + col, fB);
#pragma unroll
    for (int r = 0; r < 4; ++r) acc[r] += As[r][k] * bv;
  }

  const float bb = ldx(bias, col, fb);
#pragma unroll
  for (int r = 0; r < 4; ++r) {
    const size_t off = (size_t)(m0 + r) * N + col;
    float v = acc[r] + bb;
    if constexpr (EPI == 0) {
      out_bf[off] = f2bf(v);
    } else {
      out_f[off] = v + ldx(res, off, flags[fri]);
    }
  }
}

// ------------------------------------------------- attention (all internal bf16)
__device__ __forceinline__ int key_index(int s, int j, int S) {
  int p;
  if (j < 64)       p = s + j - 32;
  else if (j < 102) p = s + (j - 83) * 64;
  else {
    int g = j - 102;
    p = (g == 25) ? (S - 1) : (int)(((double)g * (double)(S - 1)) / 25.0);
  }
  return min(max(p, 0), S - 1);
}

__global__ __launch_bounds__(256)
void attn_kernel(const ushort_t* __restrict__ qkv, ushort_t* __restrict__ out, int S) {
  __shared__ float qs[4][64];
  __shared__ float ps[4][128];
  __shared__ int   isx[4][128];
  const int wave = threadIdx.x >> 6, lane = threadIdx.x & 63;
  const int pair = blockIdx.x * 4 + wave;   // pair = h*S + s
  const int h = pair / S;
  const int s = pair - h * S;

  const int i1 = key_index(s, lane, S);
  const int i2 = key_index(s, lane + 64, S);
  isx[wave][lane] = i1;
  isx[wave][lane + 64] = i2;
  qs[wave][lane] = bf2f(qkv[(size_t)s * (3 * D_MODEL) + h * HEAD_D + lane]);
  __syncthreads();

  const ushort_t* kb = qkv + D_MODEL + h * HEAD_D;
  const ushort_t* k1 = kb + (size_t)i1 * (3 * D_MODEL);
  const ushort_t* k2 = kb + (size_t)i2 * (3 * D_MODEL);
  float d1 = 0.f, d2 = 0.f;
  for (int c = 0; c < 64; ++c) {
    float qv = qs[wave][c];
    d1 += qv * bf2f(k1[c]);
    d2 += qv * bf2f(k2[c]);
  }
  d1 *= 0.125f; d2 *= 0.125f;
  float mx = fmaxf(d1, d2);
#pragma unroll
  for (int o = 32; o > 0; o >>= 1) mx = fmaxf(mx, __shfl_xor(mx, o));
  const float e1 = __expf(d1 - mx), e2 = __expf(d2 - mx);
  float sm = e1 + e2;
#pragma unroll
  for (int o = 32; o > 0; o >>= 1) sm += __shfl_xor(sm, o);
  const float inv = 1.0f / sm;
  ps[wave][lane] = e1 * inv;
  ps[wave][lane + 64] = e2 * inv;
  __syncthreads();

  const ushort_t* vb = qkv + 2 * D_MODEL + h * HEAD_D + lane;
  float o = 0.f;
  for (int j = 0; j < 128; ++j)
    o += ps[wave][j] * bf2f(vb[(size_t)isx[wave][j] * (3 * D_MODEL)]);
  out[(size_t)s * D_MODEL + h * HEAD_D + lane] = f2bf(o);
}

// ------------------------------------------------- fused FFN (LN2 + w1 + gelu + w2 + residual)
// One block = 4 rows. LDS: yr (residual, f32), hs (LN output), gs (gelu output).
__global__ __launch_bounds__(256)
void ffn_kernel(const float* __restrict__ y,
                const void* __restrict__ g, const void* __restrict__ b,
                const void* __restrict__ w1, const void* __restrict__ b1,
                const void* __restrict__ w2, const void* __restrict__ b2,
                void* __restrict__ out, const int* __restrict__ flags) {
  __shared__ float yr[4][512];
  __shared__ float hs[4][512];
  __shared__ float gs[4][2048];
  const int fg = flags[4], fb = flags[5], fw1 = flags[10], fb1 = flags[11];
  const int fw2 = flags[12], fb2 = flags[13], fout = flags[0];
  const int t = threadIdx.x;
  const int m0 = blockIdx.x * 4;

  for (int i = t; i < 2048; i += 256)
    yr[i >> 9][i & 511] = y[(size_t)(m0 + (i >> 9)) * 512 + (i & 511)];
  __syncthreads();

  // LN2: wave w normalizes row w
  {
    const int w = t >> 6, lane = t & 63;
    float v[8], sum = 0.f, sq = 0.f;
#pragma unroll
    for (int i = 0; i < 8; ++i) {
      v[i] = yr[w][lane * 8 + i];
      sum += v[i]; sq += v[i] * v[i];
    }
#pragma unroll
    for (int o = 32; o > 0; o >>= 1) { sum += __shfl_xor(sum, o); sq += __shfl_xor(sq, o); }
    const float mu = sum * (1.0f / 512.0f);
    const float var = sq * (1.0f / 512.0f) - mu * mu;
    const float rstd = rsqrtf(var + 1e-5f);
#pragma unroll
    for (int i = 0; i < 8; ++i) {
      int c = lane * 8 + i;
      hs[w][c] = (v[i] - mu) * rstd * ldx(g, c, fg) + ldx(b, c, fb);
    }
  }
  __syncthreads();

  // h @ w1 + b1 -> gelu -> gs
#pragma unroll
  for (int c = 0; c < 8; ++c) {
    const int col = c * 256 + t;
    float a0, a1, a2, a3;
    a0 = a1 = a2 = a3 = ldx(b1, col, fb1);
    for (int k = 0; k < 512; ++k) {
      const float wv = ldx(w1, (size_t)k * 2048 + col, fw1);
      a0 += hs[0][k] * wv; a1 += hs[1][k] * wv;
      a2 += hs[2][k] * wv; a3 += hs[3][k] * wv;
    }
    gs[0][col] = 0.5f * a0 * (1.0f + erff(a0 * 0.70710678f));
    gs[1][col] = 0.5f * a1 * (1.0f + erff(a1 * 0.70710678f));
    gs[2][col] = 0.5f * a2 * (1.0f + erff(a2 * 0.70710678f));
    gs[3][col] = 0.5f * a3 * (1.0f + erff(a3 * 0.70710678f));
  }
  __syncthreads();

  // gs @ w2 + b2 + yr -> out (dtype per fout)
#pragma unroll
  for (int c = 0; c < 2; ++c) {
    const int col = c * 256 + t;
    float a0, a1, a2, a3;
    a0 = a1 = a2 = a3 = ldx(b2, col, fb2);
    for (int k = 0; k < 2048; ++k) {
      const float wv = ldx(w2, (size_t)k * 512 + col, fw2);
      a0 += gs[0][k] * wv; a1 += gs[1][k] * wv;
      a2 += gs[2][k] * wv; a3 += gs[3][k] * wv;
    }
    float r[4] = {a0 + yr[0][col], a1 + yr[1][col], a2 + yr[2][col], a3 + yr[3][col]};
#pragma unroll
    for (int rr = 0; rr < 4; ++rr) {
      const size_t off = (size_t)(m0 + rr) * 512 + col;
      if (fout) ((float*)out)[off] = r[rr];
      else      ((ushort_t*)out)[off] = f2bf(r[rr]);
    }
  }
}

// ------------------------------------------------- launch
// ws: [0, 6291456) bytes: qkv (3sD bf16) then y (sD f32, overlays dead qkv)
//     [6291456, +56): flags[14].  Peak ~6.01 MB.
// d_out doubles as scratch: h1 -> attnb -> final out.
extern "C" void kernel_launch(void* const* d_in, const int* in_sizes, int n_in,
                              void* d_out, int out_size, void* d_ws, size_t ws_size,
                              hipStream_t stream) {
  const int S = in_sizes[0] / D_MODEL;    // 2048
  const size_t sD = (size_t)S * D_MODEL;

  ushort_t* qkv   = (ushort_t*)d_ws;                    // 3sD bf16
  float*    y     = (float*)d_ws;                       // sD f32 (after qkv dies)
  int*      flags = (int*)((char*)d_ws + 6291456);

  // per-tensor dtype flags (skip mask d_in[1])
  for (int i = 0; i < 14; ++i) {
    if (i == 1) continue;
    detect_kernel<<<1, 256, 0, stream>>>(d_in[i], in_sizes[i], flags + i);
  }

  ushort_t* h1    = (ushort_t*)d_out;   // bf16 scratch in d_out
  ushort_t* attnb = (ushort_t*)d_out;

  ln1_kernel<<<S / 4, 256, 0, stream>>>(d_in[0], d_in[2], d_in[3], h1, flags);

  gemm_simple<0><<<dim3((3 * D_MODEL) / 256, S / 4), 256, 0, stream>>>(
      h1, d_in[6], 3 * D_MODEL, d_in[7], nullptr, qkv, nullptr, flags, 6, 7, 0);

  attn_kernel<<<(S * N_HEADS) / 4, 256, 0, stream>>>(qkv, attnb, S);

  gemm_simple<2><<<dim3(D_MODEL / 256, S / 4), 256, 0, stream>>>(
      attnb, d_in[8], D_MODEL, d_in[9], d_in[0], nullptr, y, flags, 8, 9, 0);

  ffn_kernel<<<S / 4, 256, 0, stream>>>(
      y, d_in[4], d_in[5], d_in[10], d_in[11], d_in[12], d_in[13], d_out, flags);
}

// Round 6
// 558.938 us; speedup vs baseline: 2.3570x; 2.3570x over previous
//
#include <hip/hip_runtime.h>
#include <math.h>

typedef float f32x4 __attribute__((ext_vector_type(4)));
typedef short s16x8 __attribute__((ext_vector_type(8)));
typedef unsigned short u16x8 __attribute__((ext_vector_type(8)));
typedef unsigned short ushort_t;
typedef unsigned int uint_t;

#define D_MODEL 512
#define N_HEADS 8
#define HEAD_D  64
#define D_FFN   2048

__device__ __forceinline__ float bf2f(unsigned short u) {
  union { unsigned int i; float f; } c; c.i = ((unsigned int)u) << 16; return c.f;
}
__device__ __forceinline__ unsigned short f2bf(float f) {
  union { float f; unsigned int i; } c; c.f = f;
  unsigned int x = c.i;
  return (unsigned short)((x + 0x7FFFu + ((x >> 16) & 1u)) >> 16);
}
// flag-switched external load: f==1 -> buffer is f32, else bf16
__device__ __forceinline__ float ldx(const void* p, size_t i, int f) {
  return f ? ((const float*)p)[i] : bf2f(((const ushort_t*)p)[i]);
}

// ------------------------------------------------- fused dtype detector
struct DetectArgs { const void* p[14]; int n[14]; };

__global__ __launch_bounds__(256)
void detect_all(DetectArgs a, int* __restrict__ flags) {
  __shared__ int cnt[2];
  const int b = blockIdx.x;
  const int t = threadIdx.x;
  if (b == 1) { if (t == 0) flags[1] = 0; return; }   // mask: unused
  if (t == 0) { cnt[0] = 0; cnt[1] = 0; }
  __syncthreads();
  const int n_u32 = a.n[b] >> 1;
  const int sample = n_u32 < 256 ? n_u32 : 256;
  if (t < sample) {
    uint_t u = ((const uint_t*)a.p[b])[t];
    if (u != 0u) {
      atomicAdd(&cnt[0], 1);
      int e = (u >> 7) & 0xFF;
      if (e >= 0x70 && e <= 0x83) atomicAdd(&cnt[1], 1);
    }
  }
  __syncthreads();
  if (t == 0) flags[b] = (cnt[0] >= 32 && cnt[1] * 4 <= cnt[0]) ? 1 : 0;
}

// ------------------------------------------------- LN1: external x -> bf16
__global__ __launch_bounds__(256)
void ln1_kernel(const void* __restrict__ x, const void* __restrict__ g,
                const void* __restrict__ b, ushort_t* __restrict__ out,
                const int* __restrict__ flags) {
  const int fx = flags[0], fg = flags[2], fb = flags[3];
  const int row = blockIdx.x * 4 + (threadIdx.x >> 6);
  const int lane = threadIdx.x & 63;
  float v[8], sum = 0.f, sq = 0.f;
#pragma unroll
  for (int i = 0; i < 8; ++i) {
    v[i] = ldx(x, (size_t)row * D_MODEL + lane * 8 + i, fx);
    sum += v[i]; sq += v[i] * v[i];
  }
#pragma unroll
  for (int o = 32; o > 0; o >>= 1) { sum += __shfl_xor(sum, o); sq += __shfl_xor(sq, o); }
  const float mu = sum * (1.0f / D_MODEL);
  const float var = sq * (1.0f / D_MODEL) - mu * mu;
  const float rstd = rsqrtf(var + 1e-5f);
#pragma unroll
  for (int i = 0; i < 8; ++i) {
    int c = lane * 8 + i;
    out[(size_t)row * D_MODEL + c] =
        f2bf((v[i] - mu) * rstd * ldx(g, c, fg) + ldx(b, c, fb));
  }
}

// ------------------------------------------------- LN2: f32 y -> bf16
__global__ __launch_bounds__(256)
void ln2_kernel(const float* __restrict__ y, const void* __restrict__ g,
                const void* __restrict__ b, ushort_t* __restrict__ out,
                const int* __restrict__ flags) {
  const int fg = flags[4], fb = flags[5];
  const int row = blockIdx.x * 4 + (threadIdx.x >> 6);
  const int lane = threadIdx.x & 63;
  float v[8], sum = 0.f, sq = 0.f;
#pragma unroll
  for (int i = 0; i < 8; ++i) {
    v[i] = y[(size_t)row * D_MODEL + lane * 8 + i];
    sum += v[i]; sq += v[i] * v[i];
  }
#pragma unroll
  for (int o = 32; o > 0; o >>= 1) { sum += __shfl_xor(sum, o); sq += __shfl_xor(sq, o); }
  const float mu = sum * (1.0f / D_MODEL);
  const float var = sq * (1.0f / D_MODEL) - mu * mu;
  const float rstd = rsqrtf(var + 1e-5f);
#pragma unroll
  for (int i = 0; i < 8; ++i) {
    int c = lane * 8 + i;
    out[(size_t)row * D_MODEL + c] =
        f2bf((v[i] - mu) * rstd * ldx(g, c, fg) + ldx(b, c, fb));
  }
}

// ------------------------------------------------- MFMA GEMM, B in native K x N
// A: M x K bf16 internal row-major. B: external (dtype flag), element (k,n) at
// (brow0+k)*ldb + bcol0 + n. 256 threads = 2x2 waves; 16x16x32 bf16 MFMA.
// EPI: 0 = +bias -> bf16 out           1 = gelu(+bias) -> bf16 out
//      2 = +bias + res(ext) -> f32 y   3 = y += acc (+bias if addb)
template <int BM, int BN, int EPI>
__global__ __launch_bounds__(256)
void gemm_nn(const ushort_t* __restrict__ A, int lda, int K,
             const void* __restrict__ B, int ldb, int brow0, int bcol0,
             const void* __restrict__ bias, int bias_off,
             const void* __restrict__ res,
             float* __restrict__ yacc,
             ushort_t* __restrict__ out_bf, int ldo,
             const int* __restrict__ flags, int iB, int ibias, int ires, int addb) {
  constexpr int BK = 32;
  constexpr int FM = BM / 32, FN = BN / 32;
  __shared__ __attribute__((aligned(16))) ushort_t As[BM][40];
  __shared__ ushort_t Bs[BK][BN + 2];

  const int t = threadIdx.x;
  const int lane = t & 63;
  const int wave = t >> 6;
  const int wm = wave >> 1, wn = wave & 1;
  const int m0 = blockIdx.y * BM;
  const int n0 = blockIdx.x * BN;
  const int fB = flags[iB], fbias = flags[ibias];

  f32x4 acc[FM][FN];
#pragma unroll
  for (int i = 0; i < FM; ++i)
#pragma unroll
    for (int j = 0; j < FN; ++j) acc[i][j] = (f32x4)(0.0f);

  const int q = lane >> 4;
  const int lm = lane & 15;
  const int arow_s = t >> 2;       // A staging: 0..63
  const int aslot = t & 3;

  for (int k0 = 0; k0 < K; k0 += BK) {
    __syncthreads();
    // stage A (vector)
#pragma unroll
    for (int r = 0; r < BM / 64; ++r) {
      int row = r * 64 + arow_s;
      *(u16x8*)&As[row][aslot * 8] =
          *(const u16x8*)(A + (size_t)(m0 + row) * lda + k0 + aslot * 8);
    }
    // stage B (scalar ldx; includes this block's column offset n0 -- r5 bugfix)
#pragma unroll
    for (int e = 0; e < (BK * BN) / 256; ++e) {
      int id = e * 256 + t;
      int k = id / BN, n = id % BN;
      Bs[k][n] = f2bf(ldx(B, (size_t)(brow0 + k0 + k) * ldb + bcol0 + n0 + n, fB));
    }
    __syncthreads();

    s16x8 af[FM], bf[FN];
#pragma unroll
    for (int i = 0; i < FM; ++i)
      af[i] = *(const s16x8*)&As[wm * (BM / 2) + i * 16 + lm][q * 8];
#pragma unroll
    for (int j = 0; j < FN; ++j) {
      int nl = wn * (BN / 2) + j * 16 + lm;
      u16x8 tmp;
#pragma unroll
      for (int f = 0; f < 8; ++f) tmp[f] = Bs[q * 8 + f][nl];
      bf[j] = __builtin_bit_cast(s16x8, tmp);
    }
#pragma unroll
    for (int i = 0; i < FM; ++i)
#pragma unroll
      for (int j = 0; j < FN; ++j)
        acc[i][j] = __builtin_amdgcn_mfma_f32_16x16x32_bf16(af[i], bf[j], acc[i][j], 0, 0, 0);
  }

  // epilogue: C/D layout col = lane&15, row = (lane>>4)*4 + r [m89]
#pragma unroll
  for (int i = 0; i < FM; ++i) {
#pragma unroll
    for (int j = 0; j < FN; ++j) {
      const int col = wn * (BN / 2) + j * 16 + lm;
      float bb = 0.0f;
      if (EPI != 3 || addb) bb = ldx(bias, bias_off + n0 + col, fbias);
#pragma unroll
      for (int r = 0; r < 4; ++r) {
        const int rowg = m0 + wm * (BM / 2) + i * 16 + q * 4 + r;
        float v = acc[i][j][r] + bb;
        if constexpr (EPI == 0) {
          out_bf[(size_t)rowg * ldo + n0 + col] = f2bf(v);
        } else if constexpr (EPI == 1) {
          out_bf[(size_t)rowg * ldo + n0 + col] =
              f2bf(0.5f * v * (1.0f + erff(v * 0.70710678f)));
        } else if constexpr (EPI == 2) {
          const size_t off = (size_t)rowg * D_MODEL + n0 + col;
          yacc[off] = v + ldx(res, off, flags[ires]);
        } else {
          const size_t off = (size_t)rowg * D_MODEL + n0 + col;
          yacc[off] += v;
        }
      }
    }
  }
}

// ------------------------------------------------- attention (internal bf16)
__device__ __forceinline__ int key_index(int s, int j, int S) {
  int p;
  if (j < 64)       p = s + j - 32;
  else if (j < 102) p = s + (j - 83) * 64;
  else {
    int g = j - 102;
    p = (g == 25) ? (S - 1) : (int)(((double)g * (double)(S - 1)) / 25.0);
  }
  return min(max(p, 0), S - 1);
}

__global__ __launch_bounds__(256)
void attn_kernel(const ushort_t* __restrict__ qkv, ushort_t* __restrict__ out, int S) {
  __shared__ float qs[4][64];
  __shared__ float ps[4][128];
  __shared__ int   isx[4][128];
  const int wave = threadIdx.x >> 6, lane = threadIdx.x & 63;
  const int pair = blockIdx.x * 4 + wave;   // pair = h*S + s
  const int h = pair / S;
  const int s = pair - h * S;

  const int i1 = key_index(s, lane, S);
  const int i2 = key_index(s, lane + 64, S);
  isx[wave][lane] = i1;
  isx[wave][lane + 64] = i2;
  qs[wave][lane] = bf2f(qkv[(size_t)s * (3 * D_MODEL) + h * HEAD_D + lane]);
  __syncthreads();

  const ushort_t* kb = qkv + D_MODEL + h * HEAD_D;
  const ushort_t* k1 = kb + (size_t)i1 * (3 * D_MODEL);
  const ushort_t* k2 = kb + (size_t)i2 * (3 * D_MODEL);
  float d1 = 0.f, d2 = 0.f;
  for (int c = 0; c < 64; ++c) {
    float qv = qs[wave][c];
    d1 += qv * bf2f(k1[c]);
    d2 += qv * bf2f(k2[c]);
  }
  d1 *= 0.125f; d2 *= 0.125f;
  float mx = fmaxf(d1, d2);
#pragma unroll
  for (int o = 32; o > 0; o >>= 1) mx = fmaxf(mx, __shfl_xor(mx, o));
  const float e1 = __expf(d1 - mx), e2 = __expf(d2 - mx);
  float sm = e1 + e2;
#pragma unroll
  for (int o = 32; o > 0; o >>= 1) sm += __shfl_xor(sm, o);
  const float inv = 1.0f / sm;
  ps[wave][lane] = e1 * inv;
  ps[wave][lane + 64] = e2 * inv;
  __syncthreads();

  const ushort_t* vb = qkv + 2 * D_MODEL + h * HEAD_D + lane;
  float o = 0.f;
  for (int j = 0; j < 128; ++j)
    o += ps[wave][j] * bf2f(vb[(size_t)isx[wave][j] * (3 * D_MODEL)]);
  out[(size_t)s * D_MODEL + h * HEAD_D + lane] = f2bf(o);
}

// ------------------------------------------------- final convert y -> d_out
__global__ __launch_bounds__(256)
void convert_kernel(const float* __restrict__ y, void* __restrict__ out,
                    const int* __restrict__ flags, int n) {
  const int fout = flags[0];
  int i = blockIdx.x * 256 + threadIdx.x;
  if (i < n) {
    float v = y[i];
    if (fout) ((float*)out)[i] = v;
    else      ((ushort_t*)out)[i] = f2bf(v);
  }
}

// ------------------------------------------------- launch
// ws layout (phase-overlaid):
//   phase 1: qkv bf16 [0, 6MB)
//   phase 2: y f32 [0, 4MB) ; gbuf bf16 [4MB, 4MB + 8MB/P)
//   flags[14] at max(6MB, 4MB + 8MB/P)
// P (FFN column splits) from ws_size: 1 (12MB), 2 (8MB), 4 (6MB, proven).
// d_out doubles as bf16 scratch: h1 -> attnb -> h2 -> final out.
extern "C" void kernel_launch(void* const* d_in, const int* in_sizes, int n_in,
                              void* d_out, int out_size, void* d_ws, size_t ws_size,
                              hipStream_t stream) {
  const int S = in_sizes[0] / D_MODEL;    // 2048
  const size_t sD = (size_t)S * D_MODEL;
  char* ws = (char*)d_ws;

  int P;
  if      (ws_size >= 12ull * 1024 * 1024 + 4096) P = 1;
  else if (ws_size >=  8ull * 1024 * 1024 + 4096) P = 2;
  else                                            P = 4;
  const int Nc = D_FFN / P;
  const size_t gbuf_bytes = (size_t)S * Nc * 2;
  const size_t qkv_bytes  = 3 * sD * 2;
  const size_t fo = 4ull * sD + gbuf_bytes;     // y (f32) + gbuf
  const size_t flags_pos = (qkv_bytes > fo ? qkv_bytes : fo);

  ushort_t* qkv  = (ushort_t*)ws;
  float*    y    = (float*)ws;
  ushort_t* gbuf = (ushort_t*)(ws + 4 * sD);
  int*      flags = (int*)(ws + flags_pos);

  ushort_t* h1    = (ushort_t*)d_out;
  ushort_t* attnb = (ushort_t*)d_out;
  ushort_t* h2    = (ushort_t*)d_out;

  DetectArgs da;
  for (int i = 0; i < 14; ++i) { da.p[i] = d_in[i]; da.n[i] = in_sizes[i]; }
  detect_all<<<14, 256, 0, stream>>>(da, flags);

  ln1_kernel<<<S / 4, 256, 0, stream>>>(d_in[0], d_in[2], d_in[3], h1, flags);

  // GEMM1: h1 (S x 512) @ wqkv (512 x 1536) + bqkv -> qkv
  gemm_nn<128, 128, 0><<<dim3((3 * D_MODEL) / 128, S / 128), 256, 0, stream>>>(
      h1, D_MODEL, D_MODEL, d_in[6], 3 * D_MODEL, 0, 0, d_in[7], 0,
      nullptr, nullptr, qkv, 3 * D_MODEL, flags, 6, 7, 0, 1);

  attn_kernel<<<(S * N_HEADS) / 4, 256, 0, stream>>>(qkv, attnb, S);

  // GEMM2: attnb @ wo (512 x 512) + bo + x -> y (f32)
  gemm_nn<64, 64, 2><<<dim3(D_MODEL / 64, S / 64), 256, 0, stream>>>(
      attnb, D_MODEL, D_MODEL, d_in[8], D_MODEL, 0, 0, d_in[9], 0,
      d_in[0], y, nullptr, D_MODEL, flags, 8, 9, 0, 1);

  ln2_kernel<<<S / 4, 256, 0, stream>>>(y, d_in[4], d_in[5], h2, flags);

  for (int p = 0; p < P; ++p) {
    // GEMM3: h2 @ w1[:, p*Nc : (p+1)*Nc] + b1 -> gelu -> gbuf (S x Nc)
    if (Nc >= 1024) {
      gemm_nn<128, 128, 1><<<dim3(Nc / 128, S / 128), 256, 0, stream>>>(
          h2, D_MODEL, D_MODEL, d_in[10], D_FFN, 0, p * Nc, d_in[11], p * Nc,
          nullptr, nullptr, gbuf, Nc, flags, 10, 11, 0, 1);
    } else {
      gemm_nn<64, 64, 1><<<dim3(Nc / 64, S / 64), 256, 0, stream>>>(
          h2, D_MODEL, D_MODEL, d_in[10], D_FFN, 0, p * Nc, d_in[11], p * Nc,
          nullptr, nullptr, gbuf, Nc, flags, 10, 11, 0, 1);
    }
    // GEMM4: y += gbuf @ w2[p*Nc : (p+1)*Nc, :] (+ b2 on pass 0)
    gemm_nn<64, 64, 3><<<dim3(D_MODEL / 64, S / 64), 256, 0, stream>>>(
        gbuf, Nc, Nc, d_in[12], D_MODEL, p * Nc, 0, d_in[13], 0,
        nullptr, y, nullptr, D_MODEL, flags, 12, 13, 0, p == 0 ? 1 : 0);
  }

  convert_kernel<<<(int)((sD + 255) / 256), 256, 0, stream>>>(y, d_out, flags, (int)sD);
}

// Round 7
// 250.818 us; speedup vs baseline: 5.2524x; 2.2285x over previous
//
#include <hip/hip_runtime.h>
#include <math.h>

typedef float f32x4 __attribute__((ext_vector_type(4)));
typedef short s16x8 __attribute__((ext_vector_type(8)));
typedef unsigned short u16x8 __attribute__((ext_vector_type(8)));
typedef unsigned short ushort_t;
typedef unsigned int uint_t;

#define D_MODEL 512
#define N_HEADS 8
#define HEAD_D  64
#define D_FFN   2048

__device__ __forceinline__ float bf2f(unsigned short u) {
  union { unsigned int i; float f; } c; c.i = ((unsigned int)u) << 16; return c.f;
}
__device__ __forceinline__ unsigned short f2bf(float f) {
  union { float f; unsigned int i; } c; c.f = f;
  unsigned int x = c.i;
  return (unsigned short)((x + 0x7FFFu + ((x >> 16) & 1u)) >> 16);
}
__device__ __forceinline__ float ldx(const void* p, size_t i, int f) {
  return f ? ((const float*)p)[i] : bf2f(((const ushort_t*)p)[i]);
}

// ------------------------------------------------- fused dtype detector
struct DetectArgs { const void* p[14]; int n[14]; };

__global__ __launch_bounds__(256)
void detect_all(DetectArgs a, int* __restrict__ flags) {
  __shared__ int cnt[2];
  const int b = blockIdx.x;
  const int t = threadIdx.x;
  if (b == 1) { if (t == 0) flags[1] = 0; return; }
  if (t == 0) { cnt[0] = 0; cnt[1] = 0; }
  __syncthreads();
  const int n_u32 = a.n[b] >> 1;
  const int sample = n_u32 < 256 ? n_u32 : 256;
  if (t < sample) {
    uint_t u = ((const uint_t*)a.p[b])[t];
    if (u != 0u) {
      atomicAdd(&cnt[0], 1);
      int e = (u >> 7) & 0xFF;
      if (e >= 0x70 && e <= 0x83) atomicAdd(&cnt[1], 1);
    }
  }
  __syncthreads();
  if (t == 0) flags[b] = (cnt[0] >= 32 && cnt[1] * 4 <= cnt[0]) ? 1 : 0;
}

// ------------------------------------------------- weight convert+transpose
// src: Kd x Nd (dtype flag) -> dst: Nd x Kd bf16
struct WDesc { const void* src; ushort_t* dst; int Kd, Nd, flag, tile0; };

__global__ __launch_bounds__(256)
void wconv_kernel(WDesc w0, WDesc w1, WDesc w2, WDesc w3,
                  const int* __restrict__ flags) {
  __shared__ ushort_t tile[32][33];
  const int b = blockIdx.x;
  WDesc d = (b < w1.tile0) ? w0 : (b < w2.tile0) ? w1 : (b < w3.tile0) ? w2 : w3;
  const int lt = b - d.tile0;
  const int tn = d.Nd / 32;
  const int bk = lt / tn, bn = lt % tn;
  const int f = flags[d.flag];
  const int tx = threadIdx.x & 31, ty = threadIdx.x >> 5;
#pragma unroll
  for (int r = 0; r < 4; ++r) {
    int k = bk * 32 + ty * 4 + r;
    tile[ty * 4 + r][tx] = f2bf(ldx(d.src, (size_t)k * d.Nd + bn * 32 + tx, f));
  }
  __syncthreads();
#pragma unroll
  for (int r = 0; r < 4; ++r) {
    int n = bn * 32 + ty * 4 + r;
    d.dst[(size_t)n * d.Kd + bk * 32 + tx] = tile[tx][ty * 4 + r];
  }
}

// ------------------------------------------------- LN kernels
__global__ __launch_bounds__(256)
void ln1_kernel(const void* __restrict__ x, const void* __restrict__ g,
                const void* __restrict__ b, ushort_t* __restrict__ out,
                const int* __restrict__ flags) {
  const int fx = flags[0], fg = flags[2], fb = flags[3];
  const int row = blockIdx.x * 4 + (threadIdx.x >> 6);
  const int lane = threadIdx.x & 63;
  float v[8], sum = 0.f, sq = 0.f;
#pragma unroll
  for (int i = 0; i < 8; ++i) {
    v[i] = ldx(x, (size_t)row * D_MODEL + lane * 8 + i, fx);
    sum += v[i]; sq += v[i] * v[i];
  }
#pragma unroll
  for (int o = 32; o > 0; o >>= 1) { sum += __shfl_xor(sum, o); sq += __shfl_xor(sq, o); }
  const float mu = sum * (1.0f / D_MODEL);
  const float var = sq * (1.0f / D_MODEL) - mu * mu;
  const float rstd = rsqrtf(var + 1e-5f);
#pragma unroll
  for (int i = 0; i < 8; ++i) {
    int c = lane * 8 + i;
    out[(size_t)row * D_MODEL + c] =
        f2bf((v[i] - mu) * rstd * ldx(g, c, fg) + ldx(b, c, fb));
  }
}

__global__ __launch_bounds__(256)
void ln2_kernel(const float* __restrict__ y, const void* __restrict__ g,
                const void* __restrict__ b, ushort_t* __restrict__ out,
                const int* __restrict__ flags) {
  const int fg = flags[4], fb = flags[5];
  const int row = blockIdx.x * 4 + (threadIdx.x >> 6);
  const int lane = threadIdx.x & 63;
  float v[8], sum = 0.f, sq = 0.f;
#pragma unroll
  for (int i = 0; i < 8; ++i) {
    v[i] = y[(size_t)row * D_MODEL + lane * 8 + i];
    sum += v[i]; sq += v[i] * v[i];
  }
#pragma unroll
  for (int o = 32; o > 0; o >>= 1) { sum += __shfl_xor(sum, o); sq += __shfl_xor(sq, o); }
  const float mu = sum * (1.0f / D_MODEL);
  const float var = sq * (1.0f / D_MODEL) - mu * mu;
  const float rstd = rsqrtf(var + 1e-5f);
#pragma unroll
  for (int i = 0; i < 8; ++i) {
    int c = lane * 8 + i;
    out[(size_t)row * D_MODEL + c] =
        f2bf((v[i] - mu) * rstd * ldx(g, c, fg) + ldx(b, c, fb));
  }
}

// ------------------------------------------------- pipelined MFMA GEMM (A, B^T both bf16 K-contig)
// EPI: 0 = +bias -> bf16   1 = gelu(+bias) -> bf16
//      2 = atomicAdd(y, v [+bias+res at ks==0])   3 = atomicAdd(y, v [+bias at ks==0 if addb])
template <int BM, int BN, int SK, int EPI>
__global__ __launch_bounds__(256)
void gemm_bt(const ushort_t* __restrict__ A, int lda,
             const ushort_t* __restrict__ BT, int ldb, int K,
             const void* __restrict__ bias, int bias_off,
             const void* __restrict__ res,
             float* __restrict__ yacc,
             ushort_t* __restrict__ out_bf, int ldo,
             const int* __restrict__ flags, int ibias, int ires, int addb) {
  constexpr int BK = 32;
  constexpr int FM = BM / 32, FN = BN / 32;
  __shared__ __attribute__((aligned(16))) ushort_t As[BM][40];
  __shared__ __attribute__((aligned(16))) ushort_t Bs[BN][40];

  const int t = threadIdx.x;
  const int lane = t & 63, wave = t >> 6;
  const int wm = wave >> 1, wn = wave & 1;
  const int q = lane >> 4, lm = lane & 15;
  const int m0 = blockIdx.y * BM, n0 = blockIdx.x * BN;
  const int ks = (SK > 1) ? blockIdx.z : 0;
  const int kslice = K / SK, kbeg = ks * kslice, kend = kbeg + kslice;
  const int srow = t >> 2, sslot = t & 3;

  f32x4 acc[FM][FN];
#pragma unroll
  for (int i = 0; i < FM; ++i)
#pragma unroll
    for (int j = 0; j < FN; ++j) acc[i][j] = (f32x4)(0.0f);

  u16x8 av[BM / 64], bv[BN / 64];

  auto gload = [&](int k0) {
#pragma unroll
    for (int r = 0; r < BM / 64; ++r)
      av[r] = *(const u16x8*)(A + (size_t)(m0 + r * 64 + srow) * lda + k0 + sslot * 8);
#pragma unroll
    for (int r = 0; r < BN / 64; ++r)
      bv[r] = *(const u16x8*)(BT + (size_t)(n0 + r * 64 + srow) * ldb + k0 + sslot * 8);
  };
  auto swrite = [&]() {
#pragma unroll
    for (int r = 0; r < BM / 64; ++r) *(u16x8*)&As[r * 64 + srow][sslot * 8] = av[r];
#pragma unroll
    for (int r = 0; r < BN / 64; ++r) *(u16x8*)&Bs[r * 64 + srow][sslot * 8] = bv[r];
  };
  auto frag_mfma = [&]() {
    s16x8 af[FM], bf[FN];
#pragma unroll
    for (int i = 0; i < FM; ++i)
      af[i] = *(const s16x8*)&As[wm * (BM / 2) + i * 16 + lm][q * 8];
#pragma unroll
    for (int j = 0; j < FN; ++j)
      bf[j] = *(const s16x8*)&Bs[wn * (BN / 2) + j * 16 + lm][q * 8];
#pragma unroll
    for (int i = 0; i < FM; ++i)
#pragma unroll
      for (int j = 0; j < FN; ++j)
        acc[i][j] = __builtin_amdgcn_mfma_f32_16x16x32_bf16(af[i], bf[j], acc[i][j], 0, 0, 0);
  };

  gload(kbeg);
  swrite();
  __syncthreads();
  for (int k0 = kbeg + BK; k0 < kend; k0 += BK) {
    gload(k0);        // in flight during current tile's compute
    frag_mfma();
    __syncthreads();  // LDS readers done
    swrite();
    __syncthreads();  // writes visible
  }
  frag_mfma();

  const int fbias = flags[ibias];
#pragma unroll
  for (int i = 0; i < FM; ++i) {
#pragma unroll
    for (int j = 0; j < FN; ++j) {
      const int colg = n0 + wn * (BN / 2) + j * 16 + lm;
      float bb = 0.0f;
      if (EPI <= 1 || (ks == 0 && (EPI == 2 || addb)))
        bb = ldx(bias, bias_off + colg, fbias);
#pragma unroll
      for (int r = 0; r < 4; ++r) {
        const int rowg = m0 + wm * (BM / 2) + i * 16 + q * 4 + r;
        float v = acc[i][j][r] + bb;
        if constexpr (EPI == 0) {
          out_bf[(size_t)rowg * ldo + colg] = f2bf(v);
        } else if constexpr (EPI == 1) {
          out_bf[(size_t)rowg * ldo + colg] =
              f2bf(0.5f * v * (1.0f + erff(v * 0.70710678f)));
        } else if constexpr (EPI == 2) {
          const size_t off = (size_t)rowg * ldo + colg;
          if (ks == 0) v += ldx(res, off, flags[ires]);
          atomicAdd(&yacc[off], v);
        } else {
          const size_t off = (size_t)rowg * ldo + colg;
          atomicAdd(&yacc[off], v);
        }
      }
    }
  }
}

// ------------------------------------------------- legacy GEMM (fallback path, r6-proven)
template <int BM, int BN, int EPI>
__global__ __launch_bounds__(256)
void gemm_nn(const ushort_t* __restrict__ A, int lda, int K,
             const void* __restrict__ B, int ldb, int brow0, int bcol0,
             const void* __restrict__ bias, int bias_off,
             const void* __restrict__ res,
             float* __restrict__ yacc,
             ushort_t* __restrict__ out_bf, int ldo,
             const int* __restrict__ flags, int iB, int ibias, int ires, int addb) {
  constexpr int BK = 32;
  constexpr int FM = BM / 32, FN = BN / 32;
  __shared__ __attribute__((aligned(16))) ushort_t As[BM][40];
  __shared__ ushort_t Bs[BK][BN + 2];
  const int t = threadIdx.x;
  const int lane = t & 63, wave = t >> 6;
  const int wm = wave >> 1, wn = wave & 1;
  const int m0 = blockIdx.y * BM, n0 = blockIdx.x * BN;
  const int fB = flags[iB], fbias = flags[ibias];
  f32x4 acc[FM][FN];
#pragma unroll
  for (int i = 0; i < FM; ++i)
#pragma unroll
    for (int j = 0; j < FN; ++j) acc[i][j] = (f32x4)(0.0f);
  const int q = lane >> 4, lm = lane & 15;
  const int arow_s = t >> 2, aslot = t & 3;
  for (int k0 = 0; k0 < K; k0 += BK) {
    __syncthreads();
#pragma unroll
    for (int r = 0; r < BM / 64; ++r) {
      int row = r * 64 + arow_s;
      *(u16x8*)&As[row][aslot * 8] =
          *(const u16x8*)(A + (size_t)(m0 + row) * lda + k0 + aslot * 8);
    }
#pragma unroll
    for (int e = 0; e < (BK * BN) / 256; ++e) {
      int id = e * 256 + t;
      int k = id / BN, n = id % BN;
      Bs[k][n] = f2bf(ldx(B, (size_t)(brow0 + k0 + k) * ldb + bcol0 + n0 + n, fB));
    }
    __syncthreads();
    s16x8 af[FM], bf[FN];
#pragma unroll
    for (int i = 0; i < FM; ++i)
      af[i] = *(const s16x8*)&As[wm * (BM / 2) + i * 16 + lm][q * 8];
#pragma unroll
    for (int j = 0; j < FN; ++j) {
      int nl = wn * (BN / 2) + j * 16 + lm;
      u16x8 tmp;
#pragma unroll
      for (int f = 0; f < 8; ++f) tmp[f] = Bs[q * 8 + f][nl];
      bf[j] = __builtin_bit_cast(s16x8, tmp);
    }
#pragma unroll
    for (int i = 0; i < FM; ++i)
#pragma unroll
      for (int j = 0; j < FN; ++j)
        acc[i][j] = __builtin_amdgcn_mfma_f32_16x16x32_bf16(af[i], bf[j], acc[i][j], 0, 0, 0);
  }
#pragma unroll
  for (int i = 0; i < FM; ++i) {
#pragma unroll
    for (int j = 0; j < FN; ++j) {
      const int col = wn * (BN / 2) + j * 16 + lm;
      float bb = 0.0f;
      if (EPI != 3 || addb) bb = ldx(bias, bias_off + n0 + col, fbias);
#pragma unroll
      for (int r = 0; r < 4; ++r) {
        const int rowg = m0 + wm * (BM / 2) + i * 16 + q * 4 + r;
        float v = acc[i][j][r] + bb;
        if constexpr (EPI == 0) {
          out_bf[(size_t)rowg * ldo + n0 + col] = f2bf(v);
        } else if constexpr (EPI == 1) {
          out_bf[(size_t)rowg * ldo + n0 + col] =
              f2bf(0.5f * v * (1.0f + erff(v * 0.70710678f)));
        } else if constexpr (EPI == 2) {
          const size_t off = (size_t)rowg * D_MODEL + n0 + col;
          yacc[off] = v + ldx(res, off, flags[ires]);
        } else {
          const size_t off = (size_t)rowg * D_MODEL + n0 + col;
          yacc[off] += v;
        }
      }
    }
  }
}

// ------------------------------------------------- attention
__device__ __forceinline__ int key_index(int s, int j, int S) {
  int p;
  if (j < 64)       p = s + j - 32;
  else if (j < 102) p = s + (j - 83) * 64;
  else {
    int g = j - 102;
    p = (g == 25) ? (S - 1) : (int)(((double)g * (double)(S - 1)) / 25.0);
  }
  return min(max(p, 0), S - 1);
}

__global__ __launch_bounds__(256)
void attn_kernel(const ushort_t* __restrict__ qkv, ushort_t* __restrict__ out, int S) {
  __shared__ float qs[4][64];
  __shared__ float ps[4][128];
  __shared__ int   isx[4][128];
  const int wave = threadIdx.x >> 6, lane = threadIdx.x & 63;
  const int pair = blockIdx.x * 4 + wave;   // pair = h*S + s
  const int h = pair / S;
  const int s = pair - h * S;

  const int i1 = key_index(s, lane, S);
  const int i2 = key_index(s, lane + 64, S);
  isx[wave][lane] = i1;
  isx[wave][lane + 64] = i2;
  qs[wave][lane] = bf2f(qkv[(size_t)s * (3 * D_MODEL) + h * HEAD_D + lane]);
  __syncthreads();

  const ushort_t* kb = qkv + D_MODEL + h * HEAD_D;
  const ushort_t* k1 = kb + (size_t)i1 * (3 * D_MODEL);
  const ushort_t* k2 = kb + (size_t)i2 * (3 * D_MODEL);
  float d1 = 0.f, d2 = 0.f;
#pragma unroll
  for (int c = 0; c < 8; ++c) {
    u16x8 ka = *(const u16x8*)(k1 + c * 8);
    u16x8 kc = *(const u16x8*)(k2 + c * 8);
#pragma unroll
    for (int e = 0; e < 8; ++e) {
      float qv = qs[wave][c * 8 + e];
      d1 += qv * bf2f(ka[e]);
      d2 += qv * bf2f(kc[e]);
    }
  }
  d1 *= 0.125f; d2 *= 0.125f;
  float mx = fmaxf(d1, d2);
#pragma unroll
  for (int o = 32; o > 0; o >>= 1) mx = fmaxf(mx, __shfl_xor(mx, o));
  const float e1 = __expf(d1 - mx), e2 = __expf(d2 - mx);
  float sm = e1 + e2;
#pragma unroll
  for (int o = 32; o > 0; o >>= 1) sm += __shfl_xor(sm, o);
  const float inv = 1.0f / sm;
  ps[wave][lane] = e1 * inv;
  ps[wave][lane + 64] = e2 * inv;
  __syncthreads();

  const ushort_t* vb = qkv + 2 * D_MODEL + h * HEAD_D + lane;
  float o = 0.f;
  for (int j = 0; j < 128; ++j)
    o += ps[wave][j] * bf2f(vb[(size_t)isx[wave][j] * (3 * D_MODEL)]);
  out[(size_t)s * D_MODEL + h * HEAD_D + lane] = f2bf(o);
}

// ------------------------------------------------- y zero-init / final convert
__global__ __launch_bounds__(256)
void zero_kernel(float* __restrict__ y) {
  ((f32x4*)y)[blockIdx.x * 256 + threadIdx.x] = (f32x4)(0.0f);
}

__global__ __launch_bounds__(256)
void convert_kernel(const float* __restrict__ y, void* __restrict__ out,
                    const int* __restrict__ flags, int n) {
  const int fout = flags[0];
  int i = blockIdx.x * 256 + threadIdx.x;
  if (i < n) {
    float v = y[i];
    if (fout) ((float*)out)[i] = v;
    else      ((ushort_t*)out)[i] = f2bf(v);
  }
}

// ------------------------------------------------- launch
extern "C" void kernel_launch(void* const* d_in, const int* in_sizes, int n_in,
                              void* d_out, int out_size, void* d_ws, size_t ws_size,
                              hipStream_t stream) {
  const int S = in_sizes[0] / D_MODEL;    // 2048
  const size_t sD = (size_t)S * D_MODEL;
  char* ws = (char*)d_ws;

  DetectArgs da;
  for (int i = 0; i < 14; ++i) { da.p[i] = d_in[i]; da.n[i] = in_sizes[i]; }

  ushort_t* h1    = (ushort_t*)d_out;
  ushort_t* attnb = (ushort_t*)d_out;
  ushort_t* h2    = (ushort_t*)d_out;

  const size_t MB = 1024 * 1024;
  if (ws_size >= 12 * MB + 64) {
    // ---------------- primary path: bf16-transposed weights, pipelined gemm_bt
    // layout: qkv [0,6M) -> y f32 [0,4M) + gbuf [4,8M); wqkvT [6,7.5M),
    // woT [7.5,8M), w1T [8,10M), w2T [10,12M); flags @12M
    ushort_t* qkv   = (ushort_t*)ws;
    float*    y     = (float*)ws;
    ushort_t* gbuf  = (ushort_t*)(ws + 4 * MB);
    ushort_t* wqkvT = (ushort_t*)(ws + 6 * MB);
    ushort_t* woT   = (ushort_t*)(ws + 7 * MB + 512 * 1024);
    ushort_t* w1T   = (ushort_t*)(ws + 8 * MB);
    ushort_t* w2T   = (ushort_t*)(ws + 10 * MB);
    int*      flags = (int*)(ws + 12 * MB);

    detect_all<<<14, 256, 0, stream>>>(da, flags);

    WDesc dq  = { d_in[6],  wqkvT, D_MODEL, 3 * D_MODEL, 6,  0 };
    WDesc dwo = { d_in[8],  woT,   D_MODEL, D_MODEL,     8,  768 };
    WDesc dw1 = { d_in[10], w1T,   D_MODEL, D_FFN,       10, 1024 };
    WDesc dw2 = { d_in[12], w2T,   D_FFN,   D_MODEL,     12, 2048 };
    wconv_kernel<<<3072, 256, 0, stream>>>(dq, dwo, dw1, dw2, flags);

    ln1_kernel<<<S / 4, 256, 0, stream>>>(d_in[0], d_in[2], d_in[3], h1, flags);

    // GEMM1: h1 @ wqkv -> qkv  (M=S, N=1536, K=512)
    gemm_bt<64, 64, 1, 0><<<dim3(24, S / 64), 256, 0, stream>>>(
        h1, D_MODEL, wqkvT, D_MODEL, D_MODEL, d_in[7], 0,
        nullptr, nullptr, qkv, 3 * D_MODEL, flags, 7, 0, 1);

    attn_kernel<<<(S * N_HEADS) / 4, 256, 0, stream>>>(qkv, attnb, S);

    zero_kernel<<<(int)(sD / 1024), 256, 0, stream>>>(y);

    // GEMM2: attnb @ wo + bo + x -> y (split-K=2, atomic)
    gemm_bt<64, 64, 2, 2><<<dim3(8, S / 64, 2), 256, 0, stream>>>(
        attnb, D_MODEL, woT, D_MODEL, D_MODEL, d_in[9], 0,
        d_in[0], y, nullptr, D_MODEL, flags, 9, 0, 1);

    ln2_kernel<<<S / 4, 256, 0, stream>>>(y, d_in[4], d_in[5], h2, flags);

    const int Nc = D_FFN / 2;   // P=2 column split
    for (int p = 0; p < 2; ++p) {
      // GEMM3: h2 @ w1[:, slice] + b1 -> gelu -> gbuf
      gemm_bt<64, 64, 1, 1><<<dim3(Nc / 64, S / 64), 256, 0, stream>>>(
          h2, D_MODEL, w1T + (size_t)p * Nc * D_MODEL, D_MODEL, D_MODEL,
          d_in[11], p * Nc, nullptr, nullptr, gbuf, Nc, flags, 11, 0, 1);
      // GEMM4: y += gbuf @ w2[slice, :] (+b2 at p==0), split-K=2, atomic
      gemm_bt<64, 64, 2, 3><<<dim3(8, S / 64, 2), 256, 0, stream>>>(
          gbuf, Nc, w2T + (size_t)p * Nc, D_FFN, Nc, d_in[13], 0,
          nullptr, y, nullptr, D_MODEL, flags, 13, 0, p == 0 ? 1 : 0);
    }

    convert_kernel<<<(int)((sD + 255) / 256), 256, 0, stream>>>(y, d_out, flags, (int)sD);
  } else {
    // ---------------- fallback: round-6 proven path
    int P;
    if      (ws_size >= 12ull * MB + 4096) P = 1;
    else if (ws_size >=  8ull * MB + 4096) P = 2;
    else                                   P = 4;
    const int Nc = D_FFN / P;
    const size_t gbuf_bytes = (size_t)S * Nc * 2;
    const size_t qkv_bytes  = 3 * sD * 2;
    const size_t fo = 4ull * sD + gbuf_bytes;
    const size_t flags_pos = (qkv_bytes > fo ? qkv_bytes : fo);

    ushort_t* qkv  = (ushort_t*)ws;
    float*    y    = (float*)ws;
    ushort_t* gbuf = (ushort_t*)(ws + 4 * sD);
    int*      flags = (int*)(ws + flags_pos);

    detect_all<<<14, 256, 0, stream>>>(da, flags);
    ln1_kernel<<<S / 4, 256, 0, stream>>>(d_in[0], d_in[2], d_in[3], h1, flags);
    gemm_nn<128, 128, 0><<<dim3((3 * D_MODEL) / 128, S / 128), 256, 0, stream>>>(
        h1, D_MODEL, D_MODEL, d_in[6], 3 * D_MODEL, 0, 0, d_in[7], 0,
        nullptr, nullptr, qkv, 3 * D_MODEL, flags, 6, 7, 0, 1);
    attn_kernel<<<(S * N_HEADS) / 4, 256, 0, stream>>>(qkv, attnb, S);
    gemm_nn<64, 64, 2><<<dim3(D_MODEL / 64, S / 64), 256, 0, stream>>>(
        attnb, D_MODEL, D_MODEL, d_in[8], D_MODEL, 0, 0, d_in[9], 0,
        d_in[0], y, nullptr, D_MODEL, flags, 8, 9, 0, 1);
    ln2_kernel<<<S / 4, 256, 0, stream>>>(y, d_in[4], d_in[5], h2, flags);
    for (int p = 0; p < P; ++p) {
      if (Nc >= 1024) {
        gemm_nn<128, 128, 1><<<dim3(Nc / 128, S / 128), 256, 0, stream>>>(
            h2, D_MODEL, D_MODEL, d_in[10], D_FFN, 0, p * Nc, d_in[11], p * Nc,
            nullptr, nullptr, gbuf, Nc, flags, 10, 11, 0, 1);
      } else {
        gemm_nn<64, 64, 1><<<dim3(Nc / 64, S / 64), 256, 0, stream>>>(
            h2, D_MODEL, D_MODEL, d_in[10], D_FFN, 0, p * Nc, d_in[11], p * Nc,
            nullptr, nullptr, gbuf, Nc, flags, 10, 11, 0, 1);
      }
      gemm_nn<64, 64, 3><<<dim3(D_MODEL / 64, S / 64), 256, 0, stream>>>(
          gbuf, Nc, Nc, d_in[12], D_MODEL, p * Nc, 0, d_in[13], 0,
          nullptr, y, nullptr, D_MODEL, flags, 12, 13, 0, p == 0 ? 1 : 0);
    }
    convert_kernel<<<(int)((sD + 255) / 256), 256, 0, stream>>>(y, d_out, flags, (int)sD);
  }
}

// Round 8
// 247.384 us; speedup vs baseline: 5.3253x; 1.0139x over previous
//
#include <hip/hip_runtime.h>
#include <math.h>

typedef float f32x4 __attribute__((ext_vector_type(4)));
typedef short s16x8 __attribute__((ext_vector_type(8)));
typedef unsigned short u16x8 __attribute__((ext_vector_type(8)));
typedef unsigned short ushort_t;
typedef unsigned int uint_t;

#define D_MODEL 512
#define N_HEADS 8
#define HEAD_D  64
#define D_FFN   2048

__device__ __forceinline__ float bf2f(unsigned short u) {
  union { unsigned int i; float f; } c; c.i = ((unsigned int)u) << 16; return c.f;
}
__device__ __forceinline__ unsigned short f2bf(float f) {
  union { float f; unsigned int i; } c; c.f = f;
  unsigned int x = c.i;
  return (unsigned short)((x + 0x7FFFu + ((x >> 16) & 1u)) >> 16);
}
__device__ __forceinline__ float ldx(const void* p, size_t i, int f) {
  return f ? ((const float*)p)[i] : bf2f(((const ushort_t*)p)[i]);
}

// ------------------------------------------------- fused dtype detector
struct DetectArgs { const void* p[14]; int n[14]; };

__global__ __launch_bounds__(256)
void detect_all(DetectArgs a, int* __restrict__ flags) {
  __shared__ int cnt[2];
  const int b = blockIdx.x;
  const int t = threadIdx.x;
  if (b == 1) { if (t == 0) flags[1] = 0; return; }
  if (t == 0) { cnt[0] = 0; cnt[1] = 0; }
  __syncthreads();
  const int n_u32 = a.n[b] >> 1;
  const int sample = n_u32 < 256 ? n_u32 : 256;
  if (t < sample) {
    uint_t u = ((const uint_t*)a.p[b])[t];
    if (u != 0u) {
      atomicAdd(&cnt[0], 1);
      int e = (u >> 7) & 0xFF;
      if (e >= 0x70 && e <= 0x83) atomicAdd(&cnt[1], 1);
    }
  }
  __syncthreads();
  if (t == 0) flags[b] = (cnt[0] >= 32 && cnt[1] * 4 <= cnt[0]) ? 1 : 0;
}

// ------------------------------------------------- weight convert+transpose
struct WDesc { const void* src; ushort_t* dst; int Kd, Nd, flag, tile0; };

__global__ __launch_bounds__(256)
void wconv_kernel(WDesc w0, WDesc w1, WDesc w2, WDesc w3,
                  const int* __restrict__ flags) {
  __shared__ ushort_t tile[32][33];
  const int b = blockIdx.x;
  WDesc d = (b < w1.tile0) ? w0 : (b < w2.tile0) ? w1 : (b < w3.tile0) ? w2 : w3;
  const int lt = b - d.tile0;
  const int tn = d.Nd / 32;
  const int bk = lt / tn, bn = lt % tn;
  const int f = flags[d.flag];
  const int tx = threadIdx.x & 31, ty = threadIdx.x >> 5;
#pragma unroll
  for (int r = 0; r < 4; ++r) {
    int k = bk * 32 + ty * 4 + r;
    tile[ty * 4 + r][tx] = f2bf(ldx(d.src, (size_t)k * d.Nd + bn * 32 + tx, f));
  }
  __syncthreads();
#pragma unroll
  for (int r = 0; r < 4; ++r) {
    int n = bn * 32 + ty * 4 + r;
    d.dst[(size_t)n * d.Kd + bk * 32 + tx] = tile[tx][ty * 4 + r];
  }
}

// ------------------------------------------------- LN kernels
__global__ __launch_bounds__(256)
void ln1_kernel(const void* __restrict__ x, const void* __restrict__ g,
                const void* __restrict__ b, ushort_t* __restrict__ out,
                const int* __restrict__ flags) {
  const int fx = flags[0], fg = flags[2], fb = flags[3];
  const int row = blockIdx.x * 4 + (threadIdx.x >> 6);
  const int lane = threadIdx.x & 63;
  float v[8], sum = 0.f, sq = 0.f;
#pragma unroll
  for (int i = 0; i < 8; ++i) {
    v[i] = ldx(x, (size_t)row * D_MODEL + lane * 8 + i, fx);
    sum += v[i]; sq += v[i] * v[i];
  }
#pragma unroll
  for (int o = 32; o > 0; o >>= 1) { sum += __shfl_xor(sum, o); sq += __shfl_xor(sq, o); }
  const float mu = sum * (1.0f / D_MODEL);
  const float var = sq * (1.0f / D_MODEL) - mu * mu;
  const float rstd = rsqrtf(var + 1e-5f);
#pragma unroll
  for (int i = 0; i < 8; ++i) {
    int c = lane * 8 + i;
    out[(size_t)row * D_MODEL + c] =
        f2bf((v[i] - mu) * rstd * ldx(g, c, fg) + ldx(b, c, fb));
  }
}

__global__ __launch_bounds__(256)
void ln2_kernel(const float* __restrict__ y, const void* __restrict__ g,
                const void* __restrict__ b, ushort_t* __restrict__ out,
                const int* __restrict__ flags) {
  const int fg = flags[4], fb = flags[5];
  const int row = blockIdx.x * 4 + (threadIdx.x >> 6);
  const int lane = threadIdx.x & 63;
  float v[8], sum = 0.f, sq = 0.f;
#pragma unroll
  for (int i = 0; i < 8; ++i) {
    v[i] = y[(size_t)row * D_MODEL + lane * 8 + i];
    sum += v[i]; sq += v[i] * v[i];
  }
#pragma unroll
  for (int o = 32; o > 0; o >>= 1) { sum += __shfl_xor(sum, o); sq += __shfl_xor(sq, o); }
  const float mu = sum * (1.0f / D_MODEL);
  const float var = sq * (1.0f / D_MODEL) - mu * mu;
  const float rstd = rsqrtf(var + 1e-5f);
#pragma unroll
  for (int i = 0; i < 8; ++i) {
    int c = lane * 8 + i;
    out[(size_t)row * D_MODEL + c] =
        f2bf((v[i] - mu) * rstd * ldx(g, c, fg) + ldx(b, c, fb));
  }
}

// ------------------------------------------------- pipelined MFMA GEMM (A, B^T both bf16 K-contig)
// EPI: 0 = +bias -> bf16   1 = gelu(+bias) -> bf16
//      2 = atomicAdd(y, v [+bias+res at ks==0])   3 = atomicAdd(y, v [+bias at ks==0 if addb])
template <int BM, int BN, int SK, int EPI>
__global__ __launch_bounds__(256)
void gemm_bt(const ushort_t* __restrict__ A, int lda,
             const ushort_t* __restrict__ BT, int ldb, int K,
             const void* __restrict__ bias, int bias_off,
             const void* __restrict__ res,
             float* __restrict__ yacc,
             ushort_t* __restrict__ out_bf, int ldo,
             const int* __restrict__ flags, int ibias, int ires, int addb) {
  constexpr int BK = 32;
  constexpr int FM = BM / 32, FN = BN / 32;
  __shared__ __attribute__((aligned(16))) ushort_t As[BM][40];
  __shared__ __attribute__((aligned(16))) ushort_t Bs[BN][40];

  const int t = threadIdx.x;
  const int lane = t & 63, wave = t >> 6;
  const int wm = wave >> 1, wn = wave & 1;
  const int q = lane >> 4, lm = lane & 15;
  const int m0 = blockIdx.y * BM, n0 = blockIdx.x * BN;
  const int ks = (SK > 1) ? blockIdx.z : 0;
  const int kslice = K / SK, kbeg = ks * kslice, kend = kbeg + kslice;
  const int srow = t >> 2, sslot = t & 3;

  f32x4 acc[FM][FN];
#pragma unroll
  for (int i = 0; i < FM; ++i)
#pragma unroll
    for (int j = 0; j < FN; ++j) acc[i][j] = (f32x4)(0.0f);

  u16x8 av[BM / 64], bv[BN / 64];

  auto gload = [&](int k0) {
#pragma unroll
    for (int r = 0; r < BM / 64; ++r)
      av[r] = *(const u16x8*)(A + (size_t)(m0 + r * 64 + srow) * lda + k0 + sslot * 8);
#pragma unroll
    for (int r = 0; r < BN / 64; ++r)
      bv[r] = *(const u16x8*)(BT + (size_t)(n0 + r * 64 + srow) * ldb + k0 + sslot * 8);
  };
  auto swrite = [&]() {
#pragma unroll
    for (int r = 0; r < BM / 64; ++r) *(u16x8*)&As[r * 64 + srow][sslot * 8] = av[r];
#pragma unroll
    for (int r = 0; r < BN / 64; ++r) *(u16x8*)&Bs[r * 64 + srow][sslot * 8] = bv[r];
  };
  auto frag_mfma = [&]() {
    s16x8 af[FM], bf[FN];
#pragma unroll
    for (int i = 0; i < FM; ++i)
      af[i] = *(const s16x8*)&As[wm * (BM / 2) + i * 16 + lm][q * 8];
#pragma unroll
    for (int j = 0; j < FN; ++j)
      bf[j] = *(const s16x8*)&Bs[wn * (BN / 2) + j * 16 + lm][q * 8];
#pragma unroll
    for (int i = 0; i < FM; ++i)
#pragma unroll
      for (int j = 0; j < FN; ++j)
        acc[i][j] = __builtin_amdgcn_mfma_f32_16x16x32_bf16(af[i], bf[j], acc[i][j], 0, 0, 0);
  };

  gload(kbeg);
  swrite();
  __syncthreads();
  for (int k0 = kbeg + BK; k0 < kend; k0 += BK) {
    gload(k0);
    frag_mfma();
    __syncthreads();
    swrite();
    __syncthreads();
  }
  frag_mfma();

  const int fbias = flags[ibias];
#pragma unroll
  for (int i = 0; i < FM; ++i) {
#pragma unroll
    for (int j = 0; j < FN; ++j) {
      const int colg = n0 + wn * (BN / 2) + j * 16 + lm;
      float bb = 0.0f;
      if (EPI <= 1 || (ks == 0 && (EPI == 2 || addb)))
        bb = ldx(bias, bias_off + colg, fbias);
#pragma unroll
      for (int r = 0; r < 4; ++r) {
        const int rowg = m0 + wm * (BM / 2) + i * 16 + q * 4 + r;
        float v = acc[i][j][r] + bb;
        if constexpr (EPI == 0) {
          out_bf[(size_t)rowg * ldo + colg] = f2bf(v);
        } else if constexpr (EPI == 1) {
          out_bf[(size_t)rowg * ldo + colg] =
              f2bf(0.5f * v * (1.0f + erff(v * 0.70710678f)));
        } else if constexpr (EPI == 2) {
          const size_t off = (size_t)rowg * ldo + colg;
          if (ks == 0) v += ldx(res, off, flags[ires]);
          atomicAdd(&yacc[off], v);
        } else {
          const size_t off = (size_t)rowg * ldo + colg;
          atomicAdd(&yacc[off], v);
        }
      }
    }
  }
}

// ------------------------------------------------- legacy GEMM (fallback path, r6-proven)
template <int BM, int BN, int EPI>
__global__ __launch_bounds__(256)
void gemm_nn(const ushort_t* __restrict__ A, int lda, int K,
             const void* __restrict__ B, int ldb, int brow0, int bcol0,
             const void* __restrict__ bias, int bias_off,
             const void* __restrict__ res,
             float* __restrict__ yacc,
             ushort_t* __restrict__ out_bf, int ldo,
             const int* __restrict__ flags, int iB, int ibias, int ires, int addb) {
  constexpr int BK = 32;
  constexpr int FM = BM / 32, FN = BN / 32;
  __shared__ __attribute__((aligned(16))) ushort_t As[BM][40];
  __shared__ ushort_t Bs[BK][BN + 2];
  const int t = threadIdx.x;
  const int lane = t & 63, wave = t >> 6;
  const int wm = wave >> 1, wn = wave & 1;
  const int m0 = blockIdx.y * BM, n0 = blockIdx.x * BN;
  const int fB = flags[iB], fbias = flags[ibias];
  f32x4 acc[FM][FN];
#pragma unroll
  for (int i = 0; i < FM; ++i)
#pragma unroll
    for (int j = 0; j < FN; ++j) acc[i][j] = (f32x4)(0.0f);
  const int q = lane >> 4, lm = lane & 15;
  const int arow_s = t >> 2, aslot = t & 3;
  for (int k0 = 0; k0 < K; k0 += BK) {
    __syncthreads();
#pragma unroll
    for (int r = 0; r < BM / 64; ++r) {
      int row = r * 64 + arow_s;
      *(u16x8*)&As[row][aslot * 8] =
          *(const u16x8*)(A + (size_t)(m0 + row) * lda + k0 + aslot * 8);
    }
#pragma unroll
    for (int e = 0; e < (BK * BN) / 256; ++e) {
      int id = e * 256 + t;
      int k = id / BN, n = id % BN;
      Bs[k][n] = f2bf(ldx(B, (size_t)(brow0 + k0 + k) * ldb + bcol0 + n0 + n, fB));
    }
    __syncthreads();
    s16x8 af[FM], bf[FN];
#pragma unroll
    for (int i = 0; i < FM; ++i)
      af[i] = *(const s16x8*)&As[wm * (BM / 2) + i * 16 + lm][q * 8];
#pragma unroll
    for (int j = 0; j < FN; ++j) {
      int nl = wn * (BN / 2) + j * 16 + lm;
      u16x8 tmp;
#pragma unroll
      for (int f = 0; f < 8; ++f) tmp[f] = Bs[q * 8 + f][nl];
      bf[j] = __builtin_bit_cast(s16x8, tmp);
    }
#pragma unroll
    for (int i = 0; i < FM; ++i)
#pragma unroll
      for (int j = 0; j < FN; ++j)
        acc[i][j] = __builtin_amdgcn_mfma_f32_16x16x32_bf16(af[i], bf[j], acc[i][j], 0, 0, 0);
  }
#pragma unroll
  for (int i = 0; i < FM; ++i) {
#pragma unroll
    for (int j = 0; j < FN; ++j) {
      const int col = wn * (BN / 2) + j * 16 + lm;
      float bb = 0.0f;
      if (EPI != 3 || addb) bb = ldx(bias, bias_off + n0 + col, fbias);
#pragma unroll
      for (int r = 0; r < 4; ++r) {
        const int rowg = m0 + wm * (BM / 2) + i * 16 + q * 4 + r;
        float v = acc[i][j][r] + bb;
        if constexpr (EPI == 0) {
          out_bf[(size_t)rowg * ldo + n0 + col] = f2bf(v);
        } else if constexpr (EPI == 1) {
          out_bf[(size_t)rowg * ldo + n0 + col] =
              f2bf(0.5f * v * (1.0f + erff(v * 0.70710678f)));
        } else if constexpr (EPI == 2) {
          const size_t off = (size_t)rowg * D_MODEL + n0 + col;
          yacc[off] = v + ldx(res, off, flags[ires]);
        } else {
          const size_t off = (size_t)rowg * D_MODEL + n0 + col;
          yacc[off] += v;
        }
      }
    }
  }
}

// ------------------------------------------------- attention
__device__ __forceinline__ int key_index(int s, int j, int S) {
  int p;
  if (j < 64)       p = s + j - 32;
  else if (j < 102) p = s + (j - 83) * 64;
  else {
    int g = j - 102;
    p = (g == 25) ? (S - 1) : (int)(((double)g * (double)(S - 1)) / 25.0);
  }
  return min(max(p, 0), S - 1);
}

__global__ __launch_bounds__(256)
void attn_kernel(const ushort_t* __restrict__ qkv, ushort_t* __restrict__ out, int S) {
  __shared__ float qs[4][64];
  __shared__ float ps[4][128];
  __shared__ int   offs[4][128];   // element offsets: key_index * 3*D_MODEL
  const int wave = threadIdx.x >> 6, lane = threadIdx.x & 63;
  const int pair = blockIdx.x * 4 + wave;   // pair = h*S + s
  const int h = pair / S;
  const int s = pair - h * S;

  const int i1 = key_index(s, lane, S);
  const int i2 = key_index(s, lane + 64, S);
  offs[wave][lane] = i1 * (3 * D_MODEL);
  offs[wave][lane + 64] = i2 * (3 * D_MODEL);
  qs[wave][lane] = bf2f(qkv[(size_t)s * (3 * D_MODEL) + h * HEAD_D + lane]);
  __syncthreads();

  const ushort_t* kb = qkv + D_MODEL + h * HEAD_D;
  const ushort_t* k1 = kb + (size_t)i1 * (3 * D_MODEL);
  const ushort_t* k2 = kb + (size_t)i2 * (3 * D_MODEL);
  float d1 = 0.f, d2 = 0.f;
#pragma unroll
  for (int c = 0; c < 8; ++c) {
    u16x8 ka = *(const u16x8*)(k1 + c * 8);
    u16x8 kc = *(const u16x8*)(k2 + c * 8);
#pragma unroll
    for (int e = 0; e < 8; ++e) {
      float qv = qs[wave][c * 8 + e];
      d1 += qv * bf2f(ka[e]);
      d2 += qv * bf2f(kc[e]);
    }
  }
  d1 *= 0.125f; d2 *= 0.125f;
  float mx = fmaxf(d1, d2);
#pragma unroll
  for (int o = 32; o > 0; o >>= 1) mx = fmaxf(mx, __shfl_xor(mx, o));
  const float e1 = __expf(d1 - mx), e2 = __expf(d2 - mx);
  float sm = e1 + e2;
#pragma unroll
  for (int o = 32; o > 0; o >>= 1) sm += __shfl_xor(sm, o);
  const float inv = 1.0f / sm;
  ps[wave][lane] = e1 * inv;
  ps[wave][lane + 64] = e2 * inv;
  __syncthreads();

  // PV: batch-8 gather so 8 loads are in flight per step (latency / 8)
  const ushort_t* vb = qkv + 2 * D_MODEL + h * HEAD_D + lane;
  float o = 0.f;
  for (int jb = 0; jb < 128; jb += 8) {
    ushort_t vv[8];
#pragma unroll
    for (int u = 0; u < 8; ++u) vv[u] = vb[offs[wave][jb + u]];
#pragma unroll
    for (int u = 0; u < 8; ++u) o += ps[wave][jb + u] * bf2f(vv[u]);
  }
  out[(size_t)s * D_MODEL + h * HEAD_D + lane] = f2bf(o);
}

// ------------------------------------------------- y zero-init / final convert
__global__ __launch_bounds__(256)
void zero_kernel(float* __restrict__ y) {
  ((f32x4*)y)[blockIdx.x * 256 + threadIdx.x] = (f32x4)(0.0f);
}

__global__ __launch_bounds__(256)
void convert_kernel(const float* __restrict__ y, void* __restrict__ out,
                    const int* __restrict__ flags, int n) {
  const int fout = flags[0];
  int i = blockIdx.x * 256 + threadIdx.x;
  if (i < n) {
    float v = y[i];
    if (fout) ((float*)out)[i] = v;
    else      ((ushort_t*)out)[i] = f2bf(v);
  }
}

// ------------------------------------------------- launch
extern "C" void kernel_launch(void* const* d_in, const int* in_sizes, int n_in,
                              void* d_out, int out_size, void* d_ws, size_t ws_size,
                              hipStream_t stream) {
  const int S = in_sizes[0] / D_MODEL;    // 2048
  const size_t sD = (size_t)S * D_MODEL;
  char* ws = (char*)d_ws;

  DetectArgs da;
  for (int i = 0; i < 14; ++i) { da.p[i] = d_in[i]; da.n[i] = in_sizes[i]; }

  ushort_t* h1    = (ushort_t*)d_out;
  ushort_t* attnb = (ushort_t*)d_out;
  ushort_t* h2    = (ushort_t*)d_out;

  const size_t MB = 1024 * 1024;
  if (ws_size >= 12 * MB + 64) {
    // primary path: bf16-transposed weights, pipelined gemm_bt
    ushort_t* qkv   = (ushort_t*)ws;
    float*    y     = (float*)ws;
    ushort_t* gbuf  = (ushort_t*)(ws + 4 * MB);
    ushort_t* wqkvT = (ushort_t*)(ws + 6 * MB);
    ushort_t* woT   = (ushort_t*)(ws + 7 * MB + 512 * 1024);
    ushort_t* w1T   = (ushort_t*)(ws + 8 * MB);
    ushort_t* w2T   = (ushort_t*)(ws + 10 * MB);
    int*      flags = (int*)(ws + 12 * MB);

    detect_all<<<14, 256, 0, stream>>>(da, flags);

    WDesc dq  = { d_in[6],  wqkvT, D_MODEL, 3 * D_MODEL, 6,  0 };
    WDesc dwo = { d_in[8],  woT,   D_MODEL, D_MODEL,     8,  768 };
    WDesc dw1 = { d_in[10], w1T,   D_MODEL, D_FFN,       10, 1024 };
    WDesc dw2 = { d_in[12], w2T,   D_FFN,   D_MODEL,     12, 2048 };
    wconv_kernel<<<3072, 256, 0, stream>>>(dq, dwo, dw1, dw2, flags);

    ln1_kernel<<<S / 4, 256, 0, stream>>>(d_in[0], d_in[2], d_in[3], h1, flags);

    // GEMM1: h1 @ wqkv -> qkv  (M=S, N=1536, K=512), 128x64 tile (384 blocks)
    gemm_bt<128, 64, 1, 0><<<dim3(24, S / 128), 256, 0, stream>>>(
        h1, D_MODEL, wqkvT, D_MODEL, D_MODEL, d_in[7], 0,
        nullptr, nullptr, qkv, 3 * D_MODEL, flags, 7, 0, 1);

    attn_kernel<<<(S * N_HEADS) / 4, 256, 0, stream>>>(qkv, attnb, S);

    zero_kernel<<<(int)(sD / 1024), 256, 0, stream>>>(y);

    // GEMM2: attnb @ wo + bo + x -> y (split-K=2, atomic)
    gemm_bt<64, 64, 2, 2><<<dim3(8, S / 64, 2), 256, 0, stream>>>(
        attnb, D_MODEL, woT, D_MODEL, D_MODEL, d_in[9], 0,
        d_in[0], y, nullptr, D_MODEL, flags, 9, 0, 1);

    ln2_kernel<<<S / 4, 256, 0, stream>>>(y, d_in[4], d_in[5], h2, flags);

    const int Nc = D_FFN / 2;   // P=2 column split
    for (int p = 0; p < 2; ++p) {
      gemm_bt<64, 64, 1, 1><<<dim3(Nc / 64, S / 64), 256, 0, stream>>>(
          h2, D_MODEL, w1T + (size_t)p * Nc * D_MODEL, D_MODEL, D_MODEL,
          d_in[11], p * Nc, nullptr, nullptr, gbuf, Nc, flags, 11, 0, 1);
      gemm_bt<64, 64, 2, 3><<<dim3(8, S / 64, 2), 256, 0, stream>>>(
          gbuf, Nc, w2T + (size_t)p * Nc, D_FFN, Nc, d_in[13], 0,
          nullptr, y, nullptr, D_MODEL, flags, 13, 0, p == 0 ? 1 : 0);
    }

    convert_kernel<<<(int)((sD + 255) / 256), 256, 0, stream>>>(y, d_out, flags, (int)sD);
  } else {
    // fallback: round-6 proven path
    int P;
    if      (ws_size >= 12ull * MB + 4096) P = 1;
    else if (ws_size >=  8ull * MB + 4096) P = 2;
    else                                   P = 4;
    const int Nc = D_FFN / P;
    const size_t gbuf_bytes = (size_t)S * Nc * 2;
    const size_t qkv_bytes  = 3 * sD * 2;
    const size_t fo = 4ull * sD + gbuf_bytes;
    const size_t flags_pos = (qkv_bytes > fo ? qkv_bytes : fo);

    ushort_t* qkv  = (ushort_t*)ws;
    float*    y    = (float*)ws;
    ushort_t* gbuf = (ushort_t*)(ws + 4 * sD);
    int*      flags = (int*)(ws + flags_pos);

    detect_all<<<14, 256, 0, stream>>>(da, flags);
    ln1_kernel<<<S / 4, 256, 0, stream>>>(d_in[0], d_in[2], d_in[3], h1, flags);
    gemm_nn<128, 128, 0><<<dim3((3 * D_MODEL) / 128, S / 128), 256, 0, stream>>>(
        h1, D_MODEL, D_MODEL, d_in[6], 3 * D_MODEL, 0, 0, d_in[7], 0,
        nullptr, nullptr, qkv, 3 * D_MODEL, flags, 6, 7, 0, 1);
    attn_kernel<<<(S * N_HEADS) / 4, 256, 0, stream>>>(qkv, attnb, S);
    gemm_nn<64, 64, 2><<<dim3(D_MODEL / 64, S / 64), 256, 0, stream>>>(
        attnb, D_MODEL, D_MODEL, d_in[8], D_MODEL, 0, 0, d_in[9], 0,
        d_in[0], y, nullptr, D_MODEL, flags, 8, 9, 0, 1);
    ln2_kernel<<<S / 4, 256, 0, stream>>>(y, d_in[4], d_in[5], h2, flags);
    for (int p = 0; p < P; ++p) {
      if (Nc >= 1024) {
        gemm_nn<128, 128, 1><<<dim3(Nc / 128, S / 128), 256, 0, stream>>>(
            h2, D_MODEL, D_MODEL, d_in[10], D_FFN, 0, p * Nc, d_in[11], p * Nc,
            nullptr, nullptr, gbuf, Nc, flags, 10, 11, 0, 1);
      } else {
        gemm_nn<64, 64, 1><<<dim3(Nc / 64, S / 64), 256, 0, stream>>>(
            h2, D_MODEL, D_MODEL, d_in[10], D_FFN, 0, p * Nc, d_in[11], p * Nc,
            nullptr, nullptr, gbuf, Nc, flags, 10, 11, 0, 1);
      }
      gemm_nn<64, 64, 3><<<dim3(D_MODEL / 64, S / 64), 256, 0, stream>>>(
          gbuf, Nc, Nc, d_in[12], D_MODEL, p * Nc, 0, d_in[13], 0,
          nullptr, y, nullptr, D_MODEL, flags, 12, 13, 0, p == 0 ? 1 : 0);
    }
    convert_kernel<<<(int)((sD + 255) / 256), 256, 0, stream>>>(y, d_out, flags, (int)sD);
  }
}

// Round 9
// 235.234 us; speedup vs baseline: 5.6003x; 1.0517x over previous
//
#include <hip/hip_runtime.h>
#include <math.h>

typedef float f32x4 __attribute__((ext_vector_type(4)));
typedef short s16x8 __attribute__((ext_vector_type(8)));
typedef unsigned short u16x8 __attribute__((ext_vector_type(8)));
typedef unsigned short ushort_t;
typedef unsigned int uint_t;

#define D_MODEL 512
#define N_HEADS 8
#define HEAD_D  64
#define D_FFN   2048

__device__ __forceinline__ float bf2f(unsigned short u) {
  union { unsigned int i; float f; } c; c.i = ((unsigned int)u) << 16; return c.f;
}
__device__ __forceinline__ unsigned short f2bf(float f) {
  union { float f; unsigned int i; } c; c.f = f;
  unsigned int x = c.i;
  return (unsigned short)((x + 0x7FFFu + ((x >> 16) & 1u)) >> 16);
}
__device__ __forceinline__ float ldx(const void* p, size_t i, int f) {
  return f ? ((const float*)p)[i] : bf2f(((const ushort_t*)p)[i]);
}

// ------------------------------------------------- fused dtype detector
struct DetectArgs { const void* p[14]; int n[14]; };

__global__ __launch_bounds__(256)
void detect_all(DetectArgs a, int* __restrict__ flags) {
  __shared__ int cnt[2];
  const int b = blockIdx.x;
  const int t = threadIdx.x;
  if (b == 1) { if (t == 0) flags[1] = 0; return; }
  if (t == 0) { cnt[0] = 0; cnt[1] = 0; }
  __syncthreads();
  const int n_u32 = a.n[b] >> 1;
  const int sample = n_u32 < 256 ? n_u32 : 256;
  if (t < sample) {
    uint_t u = ((const uint_t*)a.p[b])[t];
    if (u != 0u) {
      atomicAdd(&cnt[0], 1);
      int e = (u >> 7) & 0xFF;
      if (e >= 0x70 && e <= 0x83) atomicAdd(&cnt[1], 1);
    }
  }
  __syncthreads();
  if (t == 0) flags[b] = (cnt[0] >= 32 && cnt[1] * 4 <= cnt[0]) ? 1 : 0;
}

// ------------------------------------------------- weight convert+transpose
struct WDesc { const void* src; ushort_t* dst; int Kd, Nd, flag, tile0; };

__global__ __launch_bounds__(256)
void wconv_kernel(WDesc w0, WDesc w1, WDesc w2, WDesc w3,
                  const int* __restrict__ flags) {
  __shared__ ushort_t tile[32][33];
  const int b = blockIdx.x;
  WDesc d = (b < w1.tile0) ? w0 : (b < w2.tile0) ? w1 : (b < w3.tile0) ? w2 : w3;
  const int lt = b - d.tile0;
  const int tn = d.Nd / 32;
  const int bk = lt / tn, bn = lt % tn;
  const int f = flags[d.flag];
  const int tx = threadIdx.x & 31, ty = threadIdx.x >> 5;
#pragma unroll
  for (int r = 0; r < 4; ++r) {
    int k = bk * 32 + ty * 4 + r;
    tile[ty * 4 + r][tx] = f2bf(ldx(d.src, (size_t)k * d.Nd + bn * 32 + tx, f));
  }
  __syncthreads();
#pragma unroll
  for (int r = 0; r < 4; ++r) {
    int n = bn * 32 + ty * 4 + r;
    d.dst[(size_t)n * d.Kd + bk * 32 + tx] = tile[tx][ty * 4 + r];
  }
}

// ------------------------------------------------- LN kernels
__global__ __launch_bounds__(256)
void ln1_kernel(const void* __restrict__ x, const void* __restrict__ g,
                const void* __restrict__ b, ushort_t* __restrict__ out,
                const int* __restrict__ flags) {
  const int fx = flags[0], fg = flags[2], fb = flags[3];
  const int row = blockIdx.x * 4 + (threadIdx.x >> 6);
  const int lane = threadIdx.x & 63;
  float v[8], sum = 0.f, sq = 0.f;
#pragma unroll
  for (int i = 0; i < 8; ++i) {
    v[i] = ldx(x, (size_t)row * D_MODEL + lane * 8 + i, fx);
    sum += v[i]; sq += v[i] * v[i];
  }
#pragma unroll
  for (int o = 32; o > 0; o >>= 1) { sum += __shfl_xor(sum, o); sq += __shfl_xor(sq, o); }
  const float mu = sum * (1.0f / D_MODEL);
  const float var = sq * (1.0f / D_MODEL) - mu * mu;
  const float rstd = rsqrtf(var + 1e-5f);
#pragma unroll
  for (int i = 0; i < 8; ++i) {
    int c = lane * 8 + i;
    out[(size_t)row * D_MODEL + c] =
        f2bf((v[i] - mu) * rstd * ldx(g, c, fg) + ldx(b, c, fb));
  }
}

__global__ __launch_bounds__(256)
void ln2_kernel(const float* __restrict__ y, const void* __restrict__ g,
                const void* __restrict__ b, ushort_t* __restrict__ out,
                const int* __restrict__ flags) {
  const int fg = flags[4], fb = flags[5];
  const int row = blockIdx.x * 4 + (threadIdx.x >> 6);
  const int lane = threadIdx.x & 63;
  float v[8], sum = 0.f, sq = 0.f;
#pragma unroll
  for (int i = 0; i < 8; ++i) {
    v[i] = y[(size_t)row * D_MODEL + lane * 8 + i];
    sum += v[i]; sq += v[i] * v[i];
  }
#pragma unroll
  for (int o = 32; o > 0; o >>= 1) { sum += __shfl_xor(sum, o); sq += __shfl_xor(sq, o); }
  const float mu = sum * (1.0f / D_MODEL);
  const float var = sq * (1.0f / D_MODEL) - mu * mu;
  const float rstd = rsqrtf(var + 1e-5f);
#pragma unroll
  for (int i = 0; i < 8; ++i) {
    int c = lane * 8 + i;
    out[(size_t)row * D_MODEL + c] =
        f2bf((v[i] - mu) * rstd * ldx(g, c, fg) + ldx(b, c, fb));
  }
}

// ------------------------------------------------- pipelined MFMA GEMM (A, B^T both bf16 K-contig)
// EPI: 0 = +bias -> bf16   1 = gelu(+bias) -> bf16
//      2 = atomicAdd(y, v [+bias+res at ks==0])   3 = atomicAdd(y, v [+bias at ks==0 if addb])
template <int BM, int BN, int SK, int EPI>
__global__ __launch_bounds__(256)
void gemm_bt(const ushort_t* __restrict__ A, int lda,
             const ushort_t* __restrict__ BT, int ldb, int K,
             const void* __restrict__ bias, int bias_off,
             const void* __restrict__ res,
             float* __restrict__ yacc,
             ushort_t* __restrict__ out_bf, int ldo,
             const int* __restrict__ flags, int ibias, int ires, int addb) {
  constexpr int BK = 32;
  constexpr int FM = BM / 32, FN = BN / 32;
  __shared__ __attribute__((aligned(16))) ushort_t As[BM][40];
  __shared__ __attribute__((aligned(16))) ushort_t Bs[BN][40];

  const int t = threadIdx.x;
  const int lane = t & 63, wave = t >> 6;
  const int wm = wave >> 1, wn = wave & 1;
  const int q = lane >> 4, lm = lane & 15;
  const int m0 = blockIdx.y * BM, n0 = blockIdx.x * BN;
  const int ks = (SK > 1) ? blockIdx.z : 0;
  const int kslice = K / SK, kbeg = ks * kslice, kend = kbeg + kslice;
  const int srow = t >> 2, sslot = t & 3;

  f32x4 acc[FM][FN];
#pragma unroll
  for (int i = 0; i < FM; ++i)
#pragma unroll
    for (int j = 0; j < FN; ++j) acc[i][j] = (f32x4)(0.0f);

  u16x8 av[BM / 64], bv[BN / 64];

  auto gload = [&](int k0) {
#pragma unroll
    for (int r = 0; r < BM / 64; ++r)
      av[r] = *(const u16x8*)(A + (size_t)(m0 + r * 64 + srow) * lda + k0 + sslot * 8);
#pragma unroll
    for (int r = 0; r < BN / 64; ++r)
      bv[r] = *(const u16x8*)(BT + (size_t)(n0 + r * 64 + srow) * ldb + k0 + sslot * 8);
  };
  auto swrite = [&]() {
#pragma unroll
    for (int r = 0; r < BM / 64; ++r) *(u16x8*)&As[r * 64 + srow][sslot * 8] = av[r];
#pragma unroll
    for (int r = 0; r < BN / 64; ++r) *(u16x8*)&Bs[r * 64 + srow][sslot * 8] = bv[r];
  };
  auto frag_mfma = [&]() {
    s16x8 af[FM], bf[FN];
#pragma unroll
    for (int i = 0; i < FM; ++i)
      af[i] = *(const s16x8*)&As[wm * (BM / 2) + i * 16 + lm][q * 8];
#pragma unroll
    for (int j = 0; j < FN; ++j)
      bf[j] = *(const s16x8*)&Bs[wn * (BN / 2) + j * 16 + lm][q * 8];
#pragma unroll
    for (int i = 0; i < FM; ++i)
#pragma unroll
      for (int j = 0; j < FN; ++j)
        acc[i][j] = __builtin_amdgcn_mfma_f32_16x16x32_bf16(af[i], bf[j], acc[i][j], 0, 0, 0);
  };

  gload(kbeg);
  swrite();
  __syncthreads();
  for (int k0 = kbeg + BK; k0 < kend; k0 += BK) {
    gload(k0);
    frag_mfma();
    __syncthreads();
    swrite();
    __syncthreads();
  }
  frag_mfma();

  const int fbias = flags[ibias];
#pragma unroll
  for (int i = 0; i < FM; ++i) {
#pragma unroll
    for (int j = 0; j < FN; ++j) {
      const int colg = n0 + wn * (BN / 2) + j * 16 + lm;
      float bb = 0.0f;
      if (EPI <= 1 || (ks == 0 && (EPI == 2 || addb)))
        bb = ldx(bias, bias_off + colg, fbias);
#pragma unroll
      for (int r = 0; r < 4; ++r) {
        const int rowg = m0 + wm * (BM / 2) + i * 16 + q * 4 + r;
        float v = acc[i][j][r] + bb;
        if constexpr (EPI == 0) {
          out_bf[(size_t)rowg * ldo + colg] = f2bf(v);
        } else if constexpr (EPI == 1) {
          out_bf[(size_t)rowg * ldo + colg] =
              f2bf(0.5f * v * (1.0f + erff(v * 0.70710678f)));
        } else if constexpr (EPI == 2) {
          const size_t off = (size_t)rowg * ldo + colg;
          if (ks == 0) v += ldx(res, off, flags[ires]);
          atomicAdd(&yacc[off], v);
        } else {
          const size_t off = (size_t)rowg * ldo + colg;
          atomicAdd(&yacc[off], v);
        }
      }
    }
  }
}

// ------------------------------------------------- legacy GEMM (fallback path, r6-proven)
template <int BM, int BN, int EPI>
__global__ __launch_bounds__(256)
void gemm_nn(const ushort_t* __restrict__ A, int lda, int K,
             const void* __restrict__ B, int ldb, int brow0, int bcol0,
             const void* __restrict__ bias, int bias_off,
             const void* __restrict__ res,
             float* __restrict__ yacc,
             ushort_t* __restrict__ out_bf, int ldo,
             const int* __restrict__ flags, int iB, int ibias, int ires, int addb) {
  constexpr int BK = 32;
  constexpr int FM = BM / 32, FN = BN / 32;
  __shared__ __attribute__((aligned(16))) ushort_t As[BM][40];
  __shared__ ushort_t Bs[BK][BN + 2];
  const int t = threadIdx.x;
  const int lane = t & 63, wave = t >> 6;
  const int wm = wave >> 1, wn = wave & 1;
  const int m0 = blockIdx.y * BM, n0 = blockIdx.x * BN;
  const int fB = flags[iB], fbias = flags[ibias];
  f32x4 acc[FM][FN];
#pragma unroll
  for (int i = 0; i < FM; ++i)
#pragma unroll
    for (int j = 0; j < FN; ++j) acc[i][j] = (f32x4)(0.0f);
  const int q = lane >> 4, lm = lane & 15;
  const int arow_s = t >> 2, aslot = t & 3;
  for (int k0 = 0; k0 < K; k0 += BK) {
    __syncthreads();
#pragma unroll
    for (int r = 0; r < BM / 64; ++r) {
      int row = r * 64 + arow_s;
      *(u16x8*)&As[row][aslot * 8] =
          *(const u16x8*)(A + (size_t)(m0 + row) * lda + k0 + aslot * 8);
    }
#pragma unroll
    for (int e = 0; e < (BK * BN) / 256; ++e) {
      int id = e * 256 + t;
      int k = id / BN, n = id % BN;
      Bs[k][n] = f2bf(ldx(B, (size_t)(brow0 + k0 + k) * ldb + bcol0 + n0 + n, fB));
    }
    __syncthreads();
    s16x8 af[FM], bf[FN];
#pragma unroll
    for (int i = 0; i < FM; ++i)
      af[i] = *(const s16x8*)&As[wm * (BM / 2) + i * 16 + lm][q * 8];
#pragma unroll
    for (int j = 0; j < FN; ++j) {
      int nl = wn * (BN / 2) + j * 16 + lm;
      u16x8 tmp;
#pragma unroll
      for (int f = 0; f < 8; ++f) tmp[f] = Bs[q * 8 + f][nl];
      bf[j] = __builtin_bit_cast(s16x8, tmp);
    }
#pragma unroll
    for (int i = 0; i < FM; ++i)
#pragma unroll
      for (int j = 0; j < FN; ++j)
        acc[i][j] = __builtin_amdgcn_mfma_f32_16x16x32_bf16(af[i], bf[j], acc[i][j], 0, 0, 0);
  }
#pragma unroll
  for (int i = 0; i < FM; ++i) {
#pragma unroll
    for (int j = 0; j < FN; ++j) {
      const int col = wn * (BN / 2) + j * 16 + lm;
      float bb = 0.0f;
      if (EPI != 3 || addb) bb = ldx(bias, bias_off + n0 + col, fbias);
#pragma unroll
      for (int r = 0; r < 4; ++r) {
        const int rowg = m0 + wm * (BM / 2) + i * 16 + q * 4 + r;
        float v = acc[i][j][r] + bb;
        if constexpr (EPI == 0) {
          out_bf[(size_t)rowg * ldo + n0 + col] = f2bf(v);
        } else if constexpr (EPI == 1) {
          out_bf[(size_t)rowg * ldo + n0 + col] =
              f2bf(0.5f * v * (1.0f + erff(v * 0.70710678f)));
        } else if constexpr (EPI == 2) {
          const size_t off = (size_t)rowg * D_MODEL + n0 + col;
          yacc[off] = v + ldx(res, off, flags[ires]);
        } else {
          const size_t off = (size_t)rowg * D_MODEL + n0 + col;
          yacc[off] += v;
        }
      }
    }
  }
}

// ------------------------------------------------- attention
__device__ __forceinline__ int key_index(int s, int j, int S) {
  int p;
  if (j < 64)       p = s + j - 32;
  else if (j < 102) p = s + (j - 83) * 64;
  else {
    int g = j - 102;
    p = (g == 25) ? (S - 1) : (int)(((double)g * (double)(S - 1)) / 25.0);
  }
  return min(max(p, 0), S - 1);
}

// one wave per (h,s). K-dot: 16 u16x8 gathers hoisted into registers (all in
// flight). PV: 8 lanes per key (u16x8 = 1 KB/instr), 8-stage rotating pipeline
// (8 outstanding HBM-miss loads/wave), shfl_xor butterfly reduce over key-groups.
// __launch_bounds__(256,4): 128-VGPR budget so the batches actually stay in
// registers (r8's 32-VGPR allocation serialized them).
__global__ __launch_bounds__(256, 4)
void attn_kernel(const ushort_t* __restrict__ qkv, ushort_t* __restrict__ out, int S) {
  __shared__ float qs[4][64];
  __shared__ float ps[4][128];
  __shared__ int   offs[4][128];   // element offsets: key_index * 3*D_MODEL
  const int wave = threadIdx.x >> 6, lane = threadIdx.x & 63;
  const int pair = blockIdx.x * 4 + wave;   // pair = h*S + s
  const int h = pair / S;
  const int s = pair - h * S;

  const int i1 = key_index(s, lane, S);
  const int i2 = key_index(s, lane + 64, S);
  offs[wave][lane] = i1 * (3 * D_MODEL);
  offs[wave][lane + 64] = i2 * (3 * D_MODEL);
  qs[wave][lane] = bf2f(qkv[(size_t)s * (3 * D_MODEL) + h * HEAD_D + lane]);
  __syncthreads();

  // ---- scores: each lane owns keys (lane, lane+64); all 16 loads in flight
  const ushort_t* kb = qkv + D_MODEL + h * HEAD_D;
  const ushort_t* k1 = kb + (size_t)i1 * (3 * D_MODEL);
  const ushort_t* k2 = kb + (size_t)i2 * (3 * D_MODEL);
  u16x8 ka[8], kc[8];
#pragma unroll
  for (int c = 0; c < 8; ++c) {
    ka[c] = *(const u16x8*)(k1 + c * 8);
    kc[c] = *(const u16x8*)(k2 + c * 8);
  }
  float d1 = 0.f, d2 = 0.f;
#pragma unroll
  for (int c = 0; c < 8; ++c) {
#pragma unroll
    for (int e = 0; e < 8; ++e) {
      float qv = qs[wave][c * 8 + e];
      d1 += qv * bf2f(ka[c][e]);
      d2 += qv * bf2f(kc[c][e]);
    }
  }
  d1 *= 0.125f; d2 *= 0.125f;
  float mx = fmaxf(d1, d2);
#pragma unroll
  for (int o = 32; o > 0; o >>= 1) mx = fmaxf(mx, __shfl_xor(mx, o));
  const float e1 = __expf(d1 - mx), e2 = __expf(d2 - mx);
  float sm = e1 + e2;
#pragma unroll
  for (int o = 32; o > 0; o >>= 1) sm += __shfl_xor(sm, o);
  const float inv = 1.0f / sm;
  ps[wave][lane] = e1 * inv;
  ps[wave][lane + 64] = e2 * inv;
  __syncthreads();

  // ---- PV: key-group g = lane>>3 (keys g, g+8, ..., g+120), dims d8..d8+7
  const int g = lane >> 3, d8 = (lane & 7) * 8;
  const ushort_t* vbase = qkv + 2 * D_MODEL + h * HEAD_D + d8;
  float oacc[8];
#pragma unroll
  for (int e = 0; e < 8; ++e) oacc[e] = 0.f;

  u16x8 vv[8];
  float pp[8];
#pragma unroll
  for (int st = 0; st < 8; ++st) {
    int j = st * 8 + g;
    vv[st] = *(const u16x8*)(vbase + offs[wave][j]);
    pp[st] = ps[wave][j];
  }
#pragma unroll
  for (int jb = 0; jb < 16; ++jb) {
    u16x8 cv = vv[jb & 7];
    float cp = pp[jb & 7];
    if (jb < 8) {
      int j = (jb + 8) * 8 + g;
      vv[jb & 7] = *(const u16x8*)(vbase + offs[wave][j]);
      pp[jb & 7] = ps[wave][j];
    }
#pragma unroll
    for (int e = 0; e < 8; ++e) oacc[e] += cp * bf2f(cv[e]);
  }
  // butterfly over the 8 key-groups (xor bits 3..5 of lane)
#pragma unroll
  for (int m = 8; m <= 32; m <<= 1)
#pragma unroll
    for (int e = 0; e < 8; ++e) oacc[e] += __shfl_xor(oacc[e], m);

  if (lane < 8) {
    u16x8 ov;
#pragma unroll
    for (int e = 0; e < 8; ++e) ov[e] = f2bf(oacc[e]);
    *(u16x8*)(out + (size_t)s * D_MODEL + h * HEAD_D + d8) = ov;
  }
}

// ------------------------------------------------- y zero-init / final convert
__global__ __launch_bounds__(256)
void zero_kernel(float* __restrict__ y) {
  ((f32x4*)y)[blockIdx.x * 256 + threadIdx.x] = (f32x4)(0.0f);
}

__global__ __launch_bounds__(256)
void convert_kernel(const float* __restrict__ y, void* __restrict__ out,
                    const int* __restrict__ flags, int n) {
  const int fout = flags[0];
  int i = blockIdx.x * 256 + threadIdx.x;
  if (i < n) {
    float v = y[i];
    if (fout) ((float*)out)[i] = v;
    else      ((ushort_t*)out)[i] = f2bf(v);
  }
}

// ------------------------------------------------- launch
extern "C" void kernel_launch(void* const* d_in, const int* in_sizes, int n_in,
                              void* d_out, int out_size, void* d_ws, size_t ws_size,
                              hipStream_t stream) {
  const int S = in_sizes[0] / D_MODEL;    // 2048
  const size_t sD = (size_t)S * D_MODEL;
  char* ws = (char*)d_ws;

  DetectArgs da;
  for (int i = 0; i < 14; ++i) { da.p[i] = d_in[i]; da.n[i] = in_sizes[i]; }

  ushort_t* h1    = (ushort_t*)d_out;
  ushort_t* attnb = (ushort_t*)d_out;
  ushort_t* h2    = (ushort_t*)d_out;

  const size_t MB = 1024 * 1024;
  if (ws_size >= 12 * MB + 64) {
    // primary path: bf16-transposed weights, pipelined gemm_bt
    ushort_t* qkv   = (ushort_t*)ws;
    float*    y     = (float*)ws;
    ushort_t* gbuf  = (ushort_t*)(ws + 4 * MB);
    ushort_t* wqkvT = (ushort_t*)(ws + 6 * MB);
    ushort_t* woT   = (ushort_t*)(ws + 7 * MB + 512 * 1024);
    ushort_t* w1T   = (ushort_t*)(ws + 8 * MB);
    ushort_t* w2T   = (ushort_t*)(ws + 10 * MB);
    int*      flags = (int*)(ws + 12 * MB);

    detect_all<<<14, 256, 0, stream>>>(da, flags);

    WDesc dq  = { d_in[6],  wqkvT, D_MODEL, 3 * D_MODEL, 6,  0 };
    WDesc dwo = { d_in[8],  woT,   D_MODEL, D_MODEL,     8,  768 };
    WDesc dw1 = { d_in[10], w1T,   D_MODEL, D_FFN,       10, 1024 };
    WDesc dw2 = { d_in[12], w2T,   D_FFN,   D_MODEL,     12, 2048 };
    wconv_kernel<<<3072, 256, 0, stream>>>(dq, dwo, dw1, dw2, flags);

    ln1_kernel<<<S / 4, 256, 0, stream>>>(d_in[0], d_in[2], d_in[3], h1, flags);

    // GEMM1: h1 @ wqkv -> qkv  (M=S, N=1536, K=512), 128x64 tile (384 blocks)
    gemm_bt<128, 64, 1, 0><<<dim3(24, S / 128), 256, 0, stream>>>(
        h1, D_MODEL, wqkvT, D_MODEL, D_MODEL, d_in[7], 0,
        nullptr, nullptr, qkv, 3 * D_MODEL, flags, 7, 0, 1);

    attn_kernel<<<(S * N_HEADS) / 4, 256, 0, stream>>>(qkv, attnb, S);

    zero_kernel<<<(int)(sD / 1024), 256, 0, stream>>>(y);

    // GEMM2: attnb @ wo + bo + x -> y (split-K=2, atomic)
    gemm_bt<64, 64, 2, 2><<<dim3(8, S / 64, 2), 256, 0, stream>>>(
        attnb, D_MODEL, woT, D_MODEL, D_MODEL, d_in[9], 0,
        d_in[0], y, nullptr, D_MODEL, flags, 9, 0, 1);

    ln2_kernel<<<S / 4, 256, 0, stream>>>(y, d_in[4], d_in[5], h2, flags);

    const int Nc = D_FFN / 2;   // P=2 column split
    for (int p = 0; p < 2; ++p) {
      gemm_bt<64, 64, 1, 1><<<dim3(Nc / 64, S / 64), 256, 0, stream>>>(
          h2, D_MODEL, w1T + (size_t)p * Nc * D_MODEL, D_MODEL, D_MODEL,
          d_in[11], p * Nc, nullptr, nullptr, gbuf, Nc, flags, 11, 0, 1);
      gemm_bt<64, 64, 2, 3><<<dim3(8, S / 64, 2), 256, 0, stream>>>(
          gbuf, Nc, w2T + (size_t)p * Nc, D_FFN, Nc, d_in[13], 0,
          nullptr, y, nullptr, D_MODEL, flags, 13, 0, p == 0 ? 1 : 0);
    }

    convert_kernel<<<(int)((sD + 255) / 256), 256, 0, stream>>>(y, d_out, flags, (int)sD);
  } else {
    // fallback: round-6 proven path
    int P;
    if      (ws_size >= 12ull * MB + 4096) P = 1;
    else if (ws_size >=  8ull * MB + 4096) P = 2;
    else                                   P = 4;
    const int Nc = D_FFN / P;
    const size_t gbuf_bytes = (size_t)S * Nc * 2;
    const size_t qkv_bytes  = 3 * sD * 2;
    const size_t fo = 4ull * sD + gbuf_bytes;
    const size_t flags_pos = (qkv_bytes > fo ? qkv_bytes : fo);

    ushort_t* qkv  = (ushort_t*)ws;
    float*    y    = (float*)ws;
    ushort_t* gbuf = (ushort_t*)(ws + 4 * sD);
    int*      flags = (int*)(ws + flags_pos);

    detect_all<<<14, 256, 0, stream>>>(da, flags);
    ln1_kernel<<<S / 4, 256, 0, stream>>>(d_in[0], d_in[2], d_in[3], h1, flags);
    gemm_nn<128, 128, 0><<<dim3((3 * D_MODEL) / 128, S / 128), 256, 0, stream>>>(
        h1, D_MODEL, D_MODEL, d_in[6], 3 * D_MODEL, 0, 0, d_in[7], 0,
        nullptr, nullptr, qkv, 3 * D_MODEL, flags, 6, 7, 0, 1);
    attn_kernel<<<(S * N_HEADS) / 4, 256, 0, stream>>>(qkv, attnb, S);
    gemm_nn<64, 64, 2><<<dim3(D_MODEL / 64, S / 64), 256, 0, stream>>>(
        attnb, D_MODEL, D_MODEL, d_in[8], D_MODEL, 0, 0, d_in[9], 0,
        d_in[0], y, nullptr, D_MODEL, flags, 8, 9, 0, 1);
    ln2_kernel<<<S / 4, 256, 0, stream>>>(y, d_in[4], d_in[5], h2, flags);
    for (int p = 0; p < P; ++p) {
      if (Nc >= 1024) {
        gemm_nn<128, 128, 1><<<dim3(Nc / 128, S / 128), 256, 0, stream>>>(
            h2, D_MODEL, D_MODEL, d_in[10], D_FFN, 0, p * Nc, d_in[11], p * Nc,
            nullptr, nullptr, gbuf, Nc, flags, 10, 11, 0, 1);
      } else {
        gemm_nn<64, 64, 1><<<dim3(Nc / 64, S / 64), 256, 0, stream>>>(
            h2, D_MODEL, D_MODEL, d_in[10], D_FFN, 0, p * Nc, d_in[11], p * Nc,
            nullptr, nullptr, gbuf, Nc, flags, 10, 11, 0, 1);
      }
      gemm_nn<64, 64, 3><<<dim3(D_MODEL / 64, S / 64), 256, 0, stream>>>(
          gbuf, Nc, Nc, d_in[12], D_MODEL, p * Nc, 0, d_in[13], 0,
          nullptr, y, nullptr, D_MODEL, flags, 12, 13, 0, p == 0 ? 1 : 0);
    }
    convert_kernel<<<(int)((sD + 255) / 256), 256, 0, stream>>>(y, d_out, flags, (int)sD);
  }
}